// Round 9
// baseline (298.910 us; speedup 1.0000x reference)
//
#include <hip/hip_runtime.h>
#include <hip/hip_bf16.h>
#include <cstdint>
#include <cstddef>

#define EMBED 1280
#define NHEAD 16
#define HD 80
#define ROT 40
#define SEQL 2048
#define QKV_N 3840
#define QKV_STRIDE (NHEAD * SEQL * HD)   // elems per Q/K/V buffer = 2,621,440

typedef __attribute__((ext_vector_type(8))) short short8v;  // 8 bf16 (4 VGPRs)
typedef __attribute__((ext_vector_type(4))) short short4v;  // 4 bf16 (8B)
typedef __attribute__((ext_vector_type(4))) float f32x4;    // MFMA accumulator

__device__ inline unsigned short f2bf(float f) {            // RNE float->bf16
    unsigned u = __float_as_uint(f);
    u += 0x7FFFu + ((u >> 16) & 1u);
    return (unsigned short)(u >> 16);
}
__device__ inline float bf2f(unsigned short h) {
    return __uint_as_float(((unsigned)h) << 16);
}

// ---------------------------------------------------------------------------
// Fused fp32 -> bf16 hi/lo split for the 3 GEMM operands (1 launch)
// ---------------------------------------------------------------------------
__global__ __launch_bounds__(256) void split3_kernel(
    const float* __restrict__ s0, unsigned short* __restrict__ h0, unsigned short* __restrict__ l0, int c0,
    const float* __restrict__ s1, unsigned short* __restrict__ h1, unsigned short* __restrict__ l1, int c1,
    const float* __restrict__ s2, unsigned short* __restrict__ h2, unsigned short* __restrict__ l2, int c2)
{
    int i = blockIdx.x * 256 + threadIdx.x;
    const float* s; unsigned short *hp, *lp; int base;
    if (i < c0)               { s = s0; hp = h0; lp = l0; base = i; }
    else if (i < c0 + c1)     { s = s1; hp = h1; lp = l1; base = i - c0; }
    else if (i < c0 + c1 + c2){ s = s2; hp = h2; lp = l2; base = i - c0 - c1; }
    else return;
    float4 v = reinterpret_cast<const float4*>(s)[base];
    unsigned short a0 = f2bf(v.x), a1 = f2bf(v.y), a2 = f2bf(v.z), a3 = f2bf(v.w);
    short4v hv, lv;
    hv[0] = (short)a0; hv[1] = (short)a1; hv[2] = (short)a2; hv[3] = (short)a3;
    lv[0] = (short)f2bf(v.x - bf2f(a0));
    lv[1] = (short)f2bf(v.y - bf2f(a1));
    lv[2] = (short)f2bf(v.z - bf2f(a2));
    lv[3] = (short)f2bf(v.w - bf2f(a3));
    *reinterpret_cast<short4v*>(&hp[base * 4]) = hv;
    *reinterpret_cast<short4v*>(&lp[base * 4]) = lv;
}

// ---------------------------------------------------------------------------
// bf16x3 split MFMA GEMM, FALLBACK variant (validated round 3; in-loop conv)
// ---------------------------------------------------------------------------
template <int MODE>
__global__ __launch_bounds__(256) void gemm_mfma_kernel(
    const float* __restrict__ A, const float* __restrict__ B,
    const float* __restrict__ bias, float* __restrict__ C,
    int M, int N, int K)
{
    __shared__ unsigned short As[2 * 128 * 32];   // 16 KB
    __shared__ unsigned short Bs[2 * 128 * 32];   // 16 KB

    const int tid  = threadIdx.x;
    const int m0   = blockIdx.y * 128;
    const int n0   = blockIdx.x * 128;
    const int wave = tid >> 6;
    const int lane = tid & 63;
    const int wm   = (wave >> 1) * 64;
    const int wn   = (wave & 1) * 64;
    const int lrow = lane & 15;
    const int lg   = lane >> 4;          // k-group 0..3

    f32x4 acc[4][4];
#pragma unroll
    for (int i = 0; i < 4; ++i)
#pragma unroll
        for (int j = 0; j < 4; ++j) acc[i][j] = (f32x4){0.f, 0.f, 0.f, 0.f};

    for (int k0 = 0; k0 < K; k0 += 32) {
        float4 ar[4], br[4];
#pragma unroll
        for (int l = 0; l < 4; ++l) {
            int id = l * 256 + tid;          // 0..1023 = 128 rows x 8 float4
            int r = id >> 3, c = id & 7;
            ar[l] = *reinterpret_cast<const float4*>(&A[(size_t)(m0 + r) * K + k0 + c * 4]);
            br[l] = *reinterpret_cast<const float4*>(&B[(size_t)(n0 + r) * K + k0 + c * 4]);
        }
        __syncthreads();
#pragma unroll
        for (int l = 0; l < 4; ++l) {
            int id = l * 256 + tid;
            int r = id >> 3, c = id & 7;
            int base = r * 32 + (((c >> 1) ^ (r & 3)) << 3) + ((c & 1) << 2);
            float4 v = ar[l];
            unsigned short h0 = f2bf(v.x), h1 = f2bf(v.y), h2 = f2bf(v.z), h3 = f2bf(v.w);
            unsigned short g0 = f2bf(v.x - bf2f(h0)), g1 = f2bf(v.y - bf2f(h1));
            unsigned short g2 = f2bf(v.z - bf2f(h2)), g3 = f2bf(v.w - bf2f(h3));
            uint2 w;
            w.x = (unsigned)h0 | ((unsigned)h1 << 16); w.y = (unsigned)h2 | ((unsigned)h3 << 16);
            *reinterpret_cast<uint2*>(&As[base]) = w;
            w.x = (unsigned)g0 | ((unsigned)g1 << 16); w.y = (unsigned)g2 | ((unsigned)g3 << 16);
            *reinterpret_cast<uint2*>(&As[4096 + base]) = w;
            v = br[l];
            h0 = f2bf(v.x); h1 = f2bf(v.y); h2 = f2bf(v.z); h3 = f2bf(v.w);
            g0 = f2bf(v.x - bf2f(h0)); g1 = f2bf(v.y - bf2f(h1));
            g2 = f2bf(v.z - bf2f(h2)); g3 = f2bf(v.w - bf2f(h3));
            w.x = (unsigned)h0 | ((unsigned)h1 << 16); w.y = (unsigned)h2 | ((unsigned)h3 << 16);
            *reinterpret_cast<uint2*>(&Bs[base]) = w;
            w.x = (unsigned)g0 | ((unsigned)g1 << 16); w.y = (unsigned)g2 | ((unsigned)g3 << 16);
            *reinterpret_cast<uint2*>(&Bs[4096 + base]) = w;
        }
        __syncthreads();
        short8v bh[4], bl[4];
#pragma unroll
        for (int fn = 0; fn < 4; ++fn) {
            int row = wn + fn * 16 + lrow;
            int idx = row * 32 + ((lg ^ (row & 3)) << 3);
            bh[fn] = *reinterpret_cast<const short8v*>(&Bs[idx]);
            bl[fn] = *reinterpret_cast<const short8v*>(&Bs[4096 + idx]);
        }
#pragma unroll
        for (int fm = 0; fm < 4; ++fm) {
            int row = wm + fm * 16 + lrow;
            int idx = row * 32 + ((lg ^ (row & 3)) << 3);
            short8v ah = *reinterpret_cast<const short8v*>(&As[idx]);
            short8v al = *reinterpret_cast<const short8v*>(&As[4096 + idx]);
#pragma unroll
            for (int fn = 0; fn < 4; ++fn) {
                acc[fm][fn] = __builtin_amdgcn_mfma_f32_16x16x32_bf16(ah, bh[fn], acc[fm][fn], 0, 0, 0);
                acc[fm][fn] = __builtin_amdgcn_mfma_f32_16x16x32_bf16(ah, bl[fn], acc[fm][fn], 0, 0, 0);
                acc[fm][fn] = __builtin_amdgcn_mfma_f32_16x16x32_bf16(al, bh[fn], acc[fm][fn], 0, 0, 0);
            }
        }
    }

#pragma unroll
    for (int fn = 0; fn < 4; ++fn) {
        int n = n0 + wn + fn * 16 + lrow;
        float bcol = bias[n];
        if (MODE == 0) {
#pragma unroll
            for (int fm = 0; fm < 4; ++fm) {
#pragma unroll
                for (int q = 0; q < 4; ++q) {
                    int m = m0 + wm + fm * 16 + lg * 4 + q;
                    C[(size_t)m * N + n] = acc[fm][fn][q] + bcol;
                }
            }
        } else {
            int part = n / EMBED;
            int rem  = n - part * EMBED;
            int head = rem / HD;
            int d    = rem - head * HD;
            float* dst = C + (size_t)part * QKV_STRIDE + (size_t)head * SEQL * HD + d;
#pragma unroll
            for (int fm = 0; fm < 4; ++fm) {
#pragma unroll
                for (int q = 0; q < 4; ++q) {
                    int m = m0 + wm + fm * 16 + lg * 4 + q;
                    dst[(size_t)m * HD] = acc[fm][fn][q] + bcol;
                }
            }
        }
    }
}

// ---------------------------------------------------------------------------
// bf16x3 split MFMA GEMM, HOISTED 2-PHASE variant: pre-split bf16 hi/lo
// operands; double-buffered LDS; next tile's global loads issued BEFORE the
// MFMA block so HBM latency hides under compute; ONE barrier per K-step
// (end-of-iter barrier proves all waves finished reading buf[cur] before it
// is overwritten in the next iteration). Fragment layout byte-identical to
// the validated kernel.
// ---------------------------------------------------------------------------
#define GSTEP(CURBUF, NXTBUF, T, PRE)                                          \
    {                                                                          \
        short8v nah[2], nal[2], nbh[2], nbl[2];                                \
        if (PRE) {                                                             \
            _Pragma("unroll")                                                  \
            for (int l = 0; l < 2; ++l) {                                      \
                int id = l * 256 + tid; int r = id >> 2, b = id & 3;           \
                size_t offA = (size_t)(m0 + r) * K + (size_t)(T + 1) * 32 + b * 8; \
                size_t offB = (size_t)(n0 + r) * K + (size_t)(T + 1) * 32 + b * 8; \
                nah[l] = *reinterpret_cast<const short8v*>(&Ah[offA]);         \
                nal[l] = *reinterpret_cast<const short8v*>(&Al[offA]);         \
                nbh[l] = *reinterpret_cast<const short8v*>(&Bh[offB]);         \
                nbl[l] = *reinterpret_cast<const short8v*>(&Bl[offB]);         \
            }                                                                  \
        }                                                                      \
        short8v fbh[4], fbl[4];                                                \
        _Pragma("unroll")                                                      \
        for (int fn = 0; fn < 4; ++fn) {                                       \
            int row = wn + fn * 16 + lrow;                                     \
            int idx = row * 32 + ((lg ^ (row & 3)) << 3);                      \
            fbh[fn] = *reinterpret_cast<const short8v*>(&Bs[CURBUF][idx]);     \
            fbl[fn] = *reinterpret_cast<const short8v*>(&Bs[CURBUF][4096 + idx]); \
        }                                                                      \
        _Pragma("unroll")                                                      \
        for (int fm = 0; fm < 4; ++fm) {                                       \
            int row = wm + fm * 16 + lrow;                                     \
            int idx = row * 32 + ((lg ^ (row & 3)) << 3);                      \
            short8v ah = *reinterpret_cast<const short8v*>(&As[CURBUF][idx]);  \
            short8v al = *reinterpret_cast<const short8v*>(&As[CURBUF][4096 + idx]); \
            _Pragma("unroll")                                                  \
            for (int fn = 0; fn < 4; ++fn) {                                   \
                acc[fm][fn] = __builtin_amdgcn_mfma_f32_16x16x32_bf16(ah, fbh[fn], acc[fm][fn], 0, 0, 0); \
                acc[fm][fn] = __builtin_amdgcn_mfma_f32_16x16x32_bf16(ah, fbl[fn], acc[fm][fn], 0, 0, 0); \
                acc[fm][fn] = __builtin_amdgcn_mfma_f32_16x16x32_bf16(al, fbh[fn], acc[fm][fn], 0, 0, 0); \
            }                                                                  \
        }                                                                      \
        if (PRE) {                                                             \
            _Pragma("unroll")                                                  \
            for (int l = 0; l < 2; ++l) {                                      \
                int id = l * 256 + tid; int r = id >> 2, b = id & 3;           \
                int base = r * 32 + ((b ^ (r & 3)) << 3);                      \
                *reinterpret_cast<short8v*>(&As[NXTBUF][base]) = nah[l];       \
                *reinterpret_cast<short8v*>(&As[NXTBUF][4096 + base]) = nal[l];\
                *reinterpret_cast<short8v*>(&Bs[NXTBUF][base]) = nbh[l];       \
                *reinterpret_cast<short8v*>(&Bs[NXTBUF][4096 + base]) = nbl[l];\
            }                                                                  \
            __syncthreads();                                                   \
        }                                                                      \
    }

template <int MODE>
__global__ __launch_bounds__(256) void gemm_mfma_pre_kernel(
    const unsigned short* __restrict__ Ah, const unsigned short* __restrict__ Al,
    const unsigned short* __restrict__ Bh, const unsigned short* __restrict__ Bl,
    const float* __restrict__ bias, float* __restrict__ C,
    int M, int N, int K)
{
    __shared__ unsigned short As[2][2 * 128 * 32];   // 2 bufs x 16 KB
    __shared__ unsigned short Bs[2][2 * 128 * 32];   // total 64 KB

    const int tid  = threadIdx.x;
    const int m0   = blockIdx.y * 128;
    const int n0   = blockIdx.x * 128;
    const int wave = tid >> 6;
    const int lane = tid & 63;
    const int wm   = (wave >> 1) * 64;
    const int wn   = (wave & 1) * 64;
    const int lrow = lane & 15;
    const int lg   = lane >> 4;          // k-group 0..3

    f32x4 acc[4][4];
#pragma unroll
    for (int i = 0; i < 4; ++i)
#pragma unroll
        for (int j = 0; j < 4; ++j) acc[i][j] = (f32x4){0.f, 0.f, 0.f, 0.f};

    // prologue: stage tile 0 into buffer 0
#pragma unroll
    for (int l = 0; l < 2; ++l) {
        int id = l * 256 + tid; int r = id >> 2, b = id & 3;
        size_t offA = (size_t)(m0 + r) * K + b * 8;
        size_t offB = (size_t)(n0 + r) * K + b * 8;
        short8v vah = *reinterpret_cast<const short8v*>(&Ah[offA]);
        short8v val = *reinterpret_cast<const short8v*>(&Al[offA]);
        short8v vbh = *reinterpret_cast<const short8v*>(&Bh[offB]);
        short8v vbl = *reinterpret_cast<const short8v*>(&Bl[offB]);
        int base = r * 32 + ((b ^ (r & 3)) << 3);
        *reinterpret_cast<short8v*>(&As[0][base]) = vah;
        *reinterpret_cast<short8v*>(&As[0][4096 + base]) = val;
        *reinterpret_cast<short8v*>(&Bs[0][base]) = vbh;
        *reinterpret_cast<short8v*>(&Bs[0][4096 + base]) = vbl;
    }
    __syncthreads();

    const int NT = K >> 5;               // 40 for both GEMMs (even)
    for (int t = 0; t < NT; t += 2) {
        GSTEP(0, 1, t, t + 1 < NT);
        if (t + 1 < NT) GSTEP(1, 0, t + 1, t + 2 < NT);
    }

#pragma unroll
    for (int fn = 0; fn < 4; ++fn) {
        int n = n0 + wn + fn * 16 + lrow;
        float bcol = bias[n];
        if (MODE == 0) {
#pragma unroll
            for (int fm = 0; fm < 4; ++fm) {
#pragma unroll
                for (int q = 0; q < 4; ++q) {
                    int m = m0 + wm + fm * 16 + lg * 4 + q;
                    C[(size_t)m * N + n] = acc[fm][fn][q] + bcol;
                }
            }
        } else {
            int part = n / EMBED;
            int rem  = n - part * EMBED;
            int head = rem / HD;
            int d    = rem - head * HD;
            float* dst = C + (size_t)part * QKV_STRIDE + (size_t)head * SEQL * HD + d;
#pragma unroll
            for (int fm = 0; fm < 4; ++fm) {
#pragma unroll
                for (int q = 0; q < 4; ++q) {
                    int m = m0 + wm + fm * 16 + lg * 4 + q;
                    dst[(size_t)m * HD] = acc[fm][fn][q] + bcol;
                }
            }
        }
    }
}

// ---------------------------------------------------------------------------
// Rotary (in-place on Q and K, [head][seq][dim] layout) — unchanged
// ---------------------------------------------------------------------------
__global__ __launch_bounds__(256) void rotary_kernel(
    float* __restrict__ Q, float* __restrict__ K, const float* __restrict__ rpe)
{
    int idx = blockIdx.x * 256 + threadIdx.x;
    int r = idx % ROT;
    int s = (idx / ROT) & (SEQL - 1);
    int h = (idx / (ROT * SEQL)) & (NHEAD - 1);
    float* buf = (idx >= NHEAD * SEQL * ROT) ? K : Q;
    float* p = buf + ((size_t)h * SEQL + s) * HD;
    float ang = rpe[s * ROT + r];
    float c = cosf(ang), sn = sinf(ang);
    float t1 = p[r], t2 = p[r + ROT];
    p[r]       = t1 * c - t2 * sn;
    p[r + ROT] = t2 * c + t1 * sn;
}

// ---------------------------------------------------------------------------
// MFMA flash attention — body byte-identical to round 4 (validated absmax
// 9.8e-4). PLANES=1: epilogue writes ctx as bf16 hi/lo planes (for the
// hoisted proj GEMM). PLANES=0: fp32 ctx (fallback path).
// ---------------------------------------------------------------------------
#define KSTR 104
#define VSTR 72
#define PSTR 72

template <int PLANES>
__global__ __launch_bounds__(256) void attn_mfma_kernel(
    const float* __restrict__ Qb, const float* __restrict__ Kb,
    const float* __restrict__ Vb, const int* __restrict__ cu, int nseg,
    float* __restrict__ ctx, unsigned short* __restrict__ ctxh,
    unsigned short* __restrict__ ctxl)
{
    __shared__ unsigned short kv_hi[64 * KSTR];   // K: [key][104] | V: [d][72]
    __shared__ unsigned short kv_lo[64 * KSTR];
    __shared__ unsigned short p_hi[64 * PSTR];
    __shared__ unsigned short p_lo[64 * PSTR];

    const int tid  = threadIdx.x;
    const int lane = tid & 63;
    const int wave = tid >> 6;
    const int lg   = lane >> 4;        // 0..3
    const int col  = lane & 15;
    const int h    = blockIdx.y;
    const int r0   = blockIdx.x * 64;
    const int wrow = wave * 16;

    // --- segment bounds: exact searchsorted(cu[1:], pos, 'right') semantics
    int qstart[4], qend[4];
#pragma unroll
    for (int q = 0; q < 4; ++q) {
        int row = r0 + wrow + lg * 4 + q;
        int sid = 0;
        for (int i = 1; i <= nseg; ++i) sid += (cu[i] <= row);
        qstart[q] = (sid == 0) ? 0 : cu[sid];
        qend[q]   = (sid >= nseg) ? SEQL : cu[sid + 1];
    }
    int blo, bhi;
    {
        int sid = 0;
        for (int i = 1; i <= nseg; ++i) sid += (cu[i] <= r0);
        blo = (sid == 0) ? 0 : cu[sid];
        sid = 0;
        for (int i = 1; i <= nseg; ++i) sid += (cu[i] <= r0 + 63);
        bhi = (sid >= nseg) ? SEQL : cu[sid + 1];
    }

    // --- Q fragments: A-row = col (wave's row wrow+col), k padded to 96
    const float scale = 0.11180339887498949f;   // 1/sqrt(80)
    short8v qh[3], qlo[3];
    {
        const float* Qr = Qb + ((size_t)h * SEQL + r0 + wrow + col) * HD;
#pragma unroll
        for (int kc = 0; kc < 3; ++kc) {
            int d0 = kc * 32 + lg * 8;
            float v[8];
            if (d0 < HD) {
                float4 f0 = *reinterpret_cast<const float4*>(&Qr[d0]);
                float4 f1 = *reinterpret_cast<const float4*>(&Qr[d0 + 4]);
                v[0] = f0.x * scale; v[1] = f0.y * scale; v[2] = f0.z * scale; v[3] = f0.w * scale;
                v[4] = f1.x * scale; v[5] = f1.y * scale; v[6] = f1.z * scale; v[7] = f1.w * scale;
            } else {
#pragma unroll
                for (int j = 0; j < 8; ++j) v[j] = 0.f;
            }
            short8v hh, ll;
#pragma unroll
            for (int j = 0; j < 8; ++j) {
                unsigned short hb = f2bf(v[j]);
                hh[j] = (short)hb;
                ll[j] = (short)f2bf(v[j] - bf2f(hb));
            }
            qh[kc] = hh; qlo[kc] = ll;
        }
    }

    f32x4 oacc[5];
#pragma unroll
    for (int fn = 0; fn < 5; ++fn) oacc[fn] = (f32x4){0.f, 0.f, 0.f, 0.f};
    float mrun[4] = {-1e30f, -1e30f, -1e30f, -1e30f};
    float lrun[4] = {0.f, 0.f, 0.f, 0.f};

    const float* Kh = Kb + (size_t)h * SEQL * HD;
    const float* Vh = Vb + (size_t)h * SEQL * HD;

    for (int kb = (blo & ~63); kb < bhi; kb += 64) {
        __syncthreads();                 // prior PV reads of kv/pbuf done

        // ---- stage K tile hi/lo: [key][KSTR], coalesced reads
        const float* Kt = Kh + (size_t)kb * HD;
#pragma unroll
        for (int l = 0; l < 5; ++l) {
            int idx = tid + l * 256;     // 64 keys x 20 float4
            int ky = idx / 20, fc = idx % 20;
            float4 f = *reinterpret_cast<const float4*>(&Kt[ky * HD + fc * 4]);
            int base = ky * KSTR + fc * 4;
            unsigned short h0 = f2bf(f.x), h1 = f2bf(f.y), h2 = f2bf(f.z), h3 = f2bf(f.w);
            uint2 w;
            w.x = (unsigned)h0 | ((unsigned)h1 << 16); w.y = (unsigned)h2 | ((unsigned)h3 << 16);
            *reinterpret_cast<uint2*>(&kv_hi[base]) = w;
            h0 = f2bf(f.x - bf2f(h0)); h1 = f2bf(f.y - bf2f(h1));
            h2 = f2bf(f.z - bf2f(h2)); h3 = f2bf(f.w - bf2f(h3));
            w.x = (unsigned)h0 | ((unsigned)h1 << 16); w.y = (unsigned)h2 | ((unsigned)h3 << 16);
            *reinterpret_cast<uint2*>(&kv_lo[base]) = w;
        }
        {   // zero-fill dims 80..95 (both planes)
            int ky = tid >> 2, off = (tid & 3) << 2;
            uint2 z; z.x = 0u; z.y = 0u;
            *reinterpret_cast<uint2*>(&kv_hi[ky * KSTR + 80 + off]) = z;
            *reinterpret_cast<uint2*>(&kv_lo[ky * KSTR + 80 + off]) = z;
        }
        __syncthreads();

        // ---- QK^T: S fragments (col=key, row=lg*4+q)
        f32x4 sfr[4];
#pragma unroll
        for (int kt = 0; kt < 4; ++kt) {
            f32x4 s = (f32x4){0.f, 0.f, 0.f, 0.f};
#pragma unroll
            for (int kc = 0; kc < 3; ++kc) {
                int bidx = (kt * 16 + col) * KSTR + kc * 32 + lg * 8;
                short8v kh = *reinterpret_cast<const short8v*>(&kv_hi[bidx]);
                short8v kl = *reinterpret_cast<const short8v*>(&kv_lo[bidx]);
                s = __builtin_amdgcn_mfma_f32_16x16x32_bf16(qh[kc],  kh, s, 0, 0, 0);
                s = __builtin_amdgcn_mfma_f32_16x16x32_bf16(qlo[kc], kh, s, 0, 0, 0);
                s = __builtin_amdgcn_mfma_f32_16x16x32_bf16(qh[kc],  kl, s, 0, 0, 0);
            }
            sfr[kt] = s;
        }
        __syncthreads();                 // all K reads done -> kv free for V

        // ---- issue V global loads early (latency hides under softmax VALU)
        const float* Vt = Vh + (size_t)kb * HD;
        float4 vreg[5];
#pragma unroll
        for (int l = 0; l < 5; ++l) {
            int idx = tid + l * 256;     // d-major: fc = idx/64, ky = idx%64
            int fc = idx >> 6, ky = idx & 63;
            vreg[l] = *reinterpret_cast<const float4*>(&Vt[ky * HD + fc * 4]);
        }

        // ---- online softmax (per q-row; row spread over 16 lanes x 4 kt)
#pragma unroll
        for (int q = 0; q < 4; ++q) {
            float sv[4];
            float mx = -1e30f;
#pragma unroll
            for (int kt = 0; kt < 4; ++kt) {
                int key = kb + kt * 16 + col;
                bool ok = (key >= qstart[q]) && (key < qend[q]);
                sv[kt] = ok ? sfr[kt][q] : -1e30f;
                mx = fmaxf(mx, sv[kt]);
            }
            mx = fmaxf(mx, __shfl_xor(mx, 1));
            mx = fmaxf(mx, __shfl_xor(mx, 2));
            mx = fmaxf(mx, __shfl_xor(mx, 4));
            mx = fmaxf(mx, __shfl_xor(mx, 8));
            float mnew  = fmaxf(mrun[q], mx);
            float alpha = __expf(mrun[q] - mnew);
            float ps = 0.f;
            int prow = (wrow + lg * 4 + q) * PSTR;
#pragma unroll
            for (int kt = 0; kt < 4; ++kt) {
                float p = (sv[kt] > -1e29f) ? __expf(sv[kt] - mnew) : 0.f;
                ps += p;
                unsigned short ph = f2bf(p);
                p_hi[prow + kt * 16 + col] = ph;
                p_lo[prow + kt * 16 + col] = f2bf(p - bf2f(ph));
            }
            ps += __shfl_xor(ps, 1);
            ps += __shfl_xor(ps, 2);
            ps += __shfl_xor(ps, 4);
            ps += __shfl_xor(ps, 8);
            lrun[q] = lrun[q] * alpha + ps;
            mrun[q] = mnew;
#pragma unroll
            for (int fn = 0; fn < 5; ++fn) oacc[fn][q] *= alpha;
        }

        // ---- write V^T to LDS [d][VSTR] (conflict-free: ky fast-varying)
#pragma unroll
        for (int l = 0; l < 5; ++l) {
            int idx = tid + l * 256;
            int fc = idx >> 6, ky = idx & 63;
            float4 f = vreg[l];
            float vv[4] = {f.x, f.y, f.z, f.w};
#pragma unroll
            for (int e = 0; e < 4; ++e) {
                unsigned short hb = f2bf(vv[e]);
                kv_hi[(fc * 4 + e) * VSTR + ky] = hb;
                kv_lo[(fc * 4 + e) * VSTR + ky] = f2bf(vv[e] - bf2f(hb));
            }
        }
        __syncthreads();                 // V + P ready

        // ---- PV: O += P * V   (A=P rows, B=V^T cols=d, k=keys)
#pragma unroll
        for (int kc2 = 0; kc2 < 2; ++kc2) {
            int aidx = (wrow + col) * PSTR + kc2 * 32 + lg * 8;
            short8v pah = *reinterpret_cast<const short8v*>(&p_hi[aidx]);
            short8v pal = *reinterpret_cast<const short8v*>(&p_lo[aidx]);
#pragma unroll
            for (int fn = 0; fn < 5; ++fn) {
                int bidx = (fn * 16 + col) * VSTR + kc2 * 32 + lg * 8;
                short8v vh = *reinterpret_cast<const short8v*>(&kv_hi[bidx]);
                short8v vl = *reinterpret_cast<const short8v*>(&kv_lo[bidx]);
                oacc[fn] = __builtin_amdgcn_mfma_f32_16x16x32_bf16(pah, vh, oacc[fn], 0, 0, 0);
                oacc[fn] = __builtin_amdgcn_mfma_f32_16x16x32_bf16(pal, vh, oacc[fn], 0, 0, 0);
                oacc[fn] = __builtin_amdgcn_mfma_f32_16x16x32_bf16(pah, vl, oacc[fn], 0, 0, 0);
            }
        }
    }

    // ---- epilogue: ctx[row][h*80 + d] = O/l (fp32 or bf16 hi/lo planes)
#pragma unroll
    for (int q = 0; q < 4; ++q) {
        float inv = 1.f / lrun[q];
        size_t rowoff = (size_t)(r0 + wrow + lg * 4 + q) * EMBED + h * HD;
        if (PLANES) {
#pragma unroll
            for (int fn = 0; fn < 5; ++fn) {
                float val = oacc[fn][q] * inv;
                unsigned short hb = f2bf(val);
                ctxh[rowoff + fn * 16 + col] = hb;
                ctxl[rowoff + fn * 16 + col] = f2bf(val - bf2f(hb));
            }
        } else {
#pragma unroll
            for (int fn = 0; fn < 5; ++fn)
                ctx[rowoff + fn * 16 + col] = oacc[fn][q] * inv;
        }
    }
}

// ---------------------------------------------------------------------------
extern "C" void kernel_launch(void* const* d_in, const int* in_sizes, int n_in,
                              void* d_out, int out_size, void* d_ws, size_t ws_size,
                              hipStream_t stream)
{
    const float* x      = (const float*)d_in[0];
    const float* rpe    = (const float*)d_in[1];
    const int*   cu     = (const int*)d_in[2];
    // d_in[3] = max_seqlen (unused)
    const float* qkv_w  = (const float*)d_in[4];
    const float* qkv_b  = (const float*)d_in[5];
    const float* proj_w = (const float*)d_in[6];
    const float* proj_b = (const float*)d_in[7];

    float* ws  = (float*)d_ws;
    float* Q   = ws;                                 // R0: fp32 2.62M
    float* K   = ws + (size_t)QKV_STRIDE;            // R1
    float* V   = ws + (size_t)2 * QKV_STRIDE;        // R2
    float* ctx = ws + (size_t)3 * QKV_STRIDE;        // R3 (10.5MB)

    const int nseg = in_sizes[2] - 1;

    // Hoisted path needs R3 (x planes) + R4 (w planes, later ctx planes)
    // + R5 (proj_w planes): 68,157,440 bytes total. (Proven present: the
    // round-6 bench ran this path.)
    const bool HOIST = ws_size >= 68157440ULL;

    if (HOIST) {
        unsigned short* xh   = (unsigned short*)(ws + (size_t)3 * QKV_STRIDE);    // R3
        unsigned short* xl   = xh + (size_t)SEQL * EMBED;
        unsigned short* wh   = (unsigned short*)(ws + (size_t)4 * QKV_STRIDE);    // R4
        unsigned short* wl   = wh + (size_t)QKV_N * EMBED;
        unsigned short* ctxh = (unsigned short*)(ws + (size_t)4 * QKV_STRIDE);    // overlays wh/wl
        unsigned short* ctxl = ctxh + (size_t)SEQL * EMBED;
        unsigned short* ph   = (unsigned short*)((char*)d_ws + 61603840);         // R5
        unsigned short* pl   = ph + (size_t)EMBED * EMBED;

        const int c0 = SEQL * EMBED / 4, c1 = QKV_N * EMBED / 4, c2 = EMBED * EMBED / 4;

        // 0) pre-split all three operands (one launch)
        split3_kernel<<<(c0 + c1 + c2 + 255) / 256, 256, 0, stream>>>(
            x, xh, xl, c0, qkv_w, wh, wl, c1, proj_w, ph, pl, c2);

        // 1) QKV projection (2-phase pipelined) -> Q/K/V [head][seq][dim]
        gemm_mfma_pre_kernel<1><<<dim3(QKV_N / 128, SEQL / 128), 256, 0, stream>>>(
            xh, xl, wh, wl, qkv_b, Q, SEQL, QKV_N, EMBED);

        // 2) rotary on Q,K in place
        rotary_kernel<<<(2 * NHEAD * SEQL * ROT) / 256, 256, 0, stream>>>(Q, K, rpe);

        // 3) attention -> ctx planes directly (w planes dead by now)
        attn_mfma_kernel<1><<<dim3(SEQL / 64, NHEAD), 256, 0, stream>>>(
            Q, K, V, cu, nseg, nullptr, ctxh, ctxl);

        // 4) output projection (2-phase pipelined)
        gemm_mfma_pre_kernel<0><<<dim3(EMBED / 128, SEQL / 128), 256, 0, stream>>>(
            ctxh, ctxl, ph, pl, proj_b, (float*)d_out, SEQL, EMBED, EMBED);
    } else {
        // fallback: fully-validated round-3 pipeline with round-4 attention
        gemm_mfma_kernel<1><<<dim3(QKV_N / 128, SEQL / 128), 256, 0, stream>>>(
            x, qkv_w, qkv_b, Q, SEQL, QKV_N, EMBED);
        rotary_kernel<<<(2 * NHEAD * SEQL * ROT) / 256, 256, 0, stream>>>(Q, K, rpe);
        attn_mfma_kernel<0><<<dim3(SEQL / 64, NHEAD), 256, 0, stream>>>(
            Q, K, V, cu, nseg, ctx, nullptr, nullptr);
        gemm_mfma_kernel<0><<<dim3(EMBED / 128, SEQL / 128), 256, 0, stream>>>(
            ctx, proj_w, proj_b, (float*)d_out, SEQL, EMBED, EMBED);
    }
}

// Round 10
// 277.744 us; speedup vs baseline: 1.0762x; 1.0762x over previous
//
#include <hip/hip_runtime.h>
#include <hip/hip_bf16.h>
#include <cstdint>
#include <cstddef>

#define EMBED 1280
#define NHEAD 16
#define HD 80
#define ROT 40
#define SEQL 2048
#define QKV_N 3840
#define QKV_STRIDE (NHEAD * SEQL * HD)   // elems per Q/K/V buffer = 2,621,440

typedef __attribute__((ext_vector_type(8))) short short8v;  // 8 bf16 (4 VGPRs)
typedef __attribute__((ext_vector_type(4))) short short4v;  // 4 bf16 (8B)
typedef __attribute__((ext_vector_type(4))) float f32x4;    // MFMA accumulator

__device__ inline unsigned short f2bf(float f) {            // RNE float->bf16
    unsigned u = __float_as_uint(f);
    u += 0x7FFFu + ((u >> 16) & 1u);
    return (unsigned short)(u >> 16);
}
__device__ inline float bf2f(unsigned short h) {
    return __uint_as_float(((unsigned)h) << 16);
}

// 16B async global->LDS (linear dest = wave base + lane*16; size literal 16)
#define GLD16(GP, LP)                                                         \
    __builtin_amdgcn_global_load_lds(                                         \
        (const __attribute__((address_space(1))) unsigned int*)(GP),          \
        (__attribute__((address_space(3))) unsigned int*)(LP), 16, 0, 0)

// ---------------------------------------------------------------------------
// Fused fp32 -> bf16 hi/lo split for the 3 GEMM operands (1 launch)
// ---------------------------------------------------------------------------
__global__ __launch_bounds__(256) void split3_kernel(
    const float* __restrict__ s0, unsigned short* __restrict__ h0, unsigned short* __restrict__ l0, int c0,
    const float* __restrict__ s1, unsigned short* __restrict__ h1, unsigned short* __restrict__ l1, int c1,
    const float* __restrict__ s2, unsigned short* __restrict__ h2, unsigned short* __restrict__ l2, int c2)
{
    int i = blockIdx.x * 256 + threadIdx.x;
    const float* s; unsigned short *hp, *lp; int base;
    if (i < c0)               { s = s0; hp = h0; lp = l0; base = i; }
    else if (i < c0 + c1)     { s = s1; hp = h1; lp = l1; base = i - c0; }
    else if (i < c0 + c1 + c2){ s = s2; hp = h2; lp = l2; base = i - c0 - c1; }
    else return;
    float4 v = reinterpret_cast<const float4*>(s)[base];
    unsigned short a0 = f2bf(v.x), a1 = f2bf(v.y), a2 = f2bf(v.z), a3 = f2bf(v.w);
    short4v hv, lv;
    hv[0] = (short)a0; hv[1] = (short)a1; hv[2] = (short)a2; hv[3] = (short)a3;
    lv[0] = (short)f2bf(v.x - bf2f(a0));
    lv[1] = (short)f2bf(v.y - bf2f(a1));
    lv[2] = (short)f2bf(v.z - bf2f(a2));
    lv[3] = (short)f2bf(v.w - bf2f(a3));
    *reinterpret_cast<short4v*>(&hp[base * 4]) = hv;
    *reinterpret_cast<short4v*>(&lp[base * 4]) = lv;
}

// ---------------------------------------------------------------------------
// bf16x3 split MFMA GEMM, FALLBACK variant (validated round 3; in-loop conv)
// ---------------------------------------------------------------------------
template <int MODE>
__global__ __launch_bounds__(256) void gemm_mfma_kernel(
    const float* __restrict__ A, const float* __restrict__ B,
    const float* __restrict__ bias, float* __restrict__ C,
    int M, int N, int K)
{
    __shared__ unsigned short As[2 * 128 * 32];   // 16 KB
    __shared__ unsigned short Bs[2 * 128 * 32];   // 16 KB

    const int tid  = threadIdx.x;
    const int m0   = blockIdx.y * 128;
    const int n0   = blockIdx.x * 128;
    const int wave = tid >> 6;
    const int lane = tid & 63;
    const int wm   = (wave >> 1) * 64;
    const int wn   = (wave & 1) * 64;
    const int lrow = lane & 15;
    const int lg   = lane >> 4;          // k-group 0..3

    f32x4 acc[4][4];
#pragma unroll
    for (int i = 0; i < 4; ++i)
#pragma unroll
        for (int j = 0; j < 4; ++j) acc[i][j] = (f32x4){0.f, 0.f, 0.f, 0.f};

    for (int k0 = 0; k0 < K; k0 += 32) {
        float4 ar[4], br[4];
#pragma unroll
        for (int l = 0; l < 4; ++l) {
            int id = l * 256 + tid;          // 0..1023 = 128 rows x 8 float4
            int r = id >> 3, c = id & 7;
            ar[l] = *reinterpret_cast<const float4*>(&A[(size_t)(m0 + r) * K + k0 + c * 4]);
            br[l] = *reinterpret_cast<const float4*>(&B[(size_t)(n0 + r) * K + k0 + c * 4]);
        }
        __syncthreads();
#pragma unroll
        for (int l = 0; l < 4; ++l) {
            int id = l * 256 + tid;
            int r = id >> 3, c = id & 7;
            int base = r * 32 + (((c >> 1) ^ (r & 3)) << 3) + ((c & 1) << 2);
            float4 v = ar[l];
            unsigned short h0 = f2bf(v.x), h1 = f2bf(v.y), h2 = f2bf(v.z), h3 = f2bf(v.w);
            unsigned short g0 = f2bf(v.x - bf2f(h0)), g1 = f2bf(v.y - bf2f(h1));
            unsigned short g2 = f2bf(v.z - bf2f(h2)), g3 = f2bf(v.w - bf2f(h3));
            uint2 w;
            w.x = (unsigned)h0 | ((unsigned)h1 << 16); w.y = (unsigned)h2 | ((unsigned)h3 << 16);
            *reinterpret_cast<uint2*>(&As[base]) = w;
            w.x = (unsigned)g0 | ((unsigned)g1 << 16); w.y = (unsigned)g2 | ((unsigned)g3 << 16);
            *reinterpret_cast<uint2*>(&As[4096 + base]) = w;
            v = br[l];
            h0 = f2bf(v.x); h1 = f2bf(v.y); h2 = f2bf(v.z); h3 = f2bf(v.w);
            g0 = f2bf(v.x - bf2f(h0)); g1 = f2bf(v.y - bf2f(h1));
            g2 = f2bf(v.z - bf2f(h2)); g3 = f2bf(v.w - bf2f(h3));
            w.x = (unsigned)h0 | ((unsigned)h1 << 16); w.y = (unsigned)h2 | ((unsigned)h3 << 16);
            *reinterpret_cast<uint2*>(&Bs[base]) = w;
            w.x = (unsigned)g0 | ((unsigned)g1 << 16); w.y = (unsigned)g2 | ((unsigned)g3 << 16);
            *reinterpret_cast<uint2*>(&Bs[4096 + base]) = w;
        }
        __syncthreads();
        short8v bh[4], bl[4];
#pragma unroll
        for (int fn = 0; fn < 4; ++fn) {
            int row = wn + fn * 16 + lrow;
            int idx = row * 32 + ((lg ^ (row & 3)) << 3);
            bh[fn] = *reinterpret_cast<const short8v*>(&Bs[idx]);
            bl[fn] = *reinterpret_cast<const short8v*>(&Bs[4096 + idx]);
        }
#pragma unroll
        for (int fm = 0; fm < 4; ++fm) {
            int row = wm + fm * 16 + lrow;
            int idx = row * 32 + ((lg ^ (row & 3)) << 3);
            short8v ah = *reinterpret_cast<const short8v*>(&As[idx]);
            short8v al = *reinterpret_cast<const short8v*>(&As[4096 + idx]);
#pragma unroll
            for (int fn = 0; fn < 4; ++fn) {
                acc[fm][fn] = __builtin_amdgcn_mfma_f32_16x16x32_bf16(ah, bh[fn], acc[fm][fn], 0, 0, 0);
                acc[fm][fn] = __builtin_amdgcn_mfma_f32_16x16x32_bf16(ah, bl[fn], acc[fm][fn], 0, 0, 0);
                acc[fm][fn] = __builtin_amdgcn_mfma_f32_16x16x32_bf16(al, bh[fn], acc[fm][fn], 0, 0, 0);
            }
        }
    }

#pragma unroll
    for (int fn = 0; fn < 4; ++fn) {
        int n = n0 + wn + fn * 16 + lrow;
        float bcol = bias[n];
        if (MODE == 0) {
#pragma unroll
            for (int fm = 0; fm < 4; ++fm) {
#pragma unroll
                for (int q = 0; q < 4; ++q) {
                    int m = m0 + wm + fm * 16 + lg * 4 + q;
                    C[(size_t)m * N + n] = acc[fm][fn][q] + bcol;
                }
            }
        } else {
            int part = n / EMBED;
            int rem  = n - part * EMBED;
            int head = rem / HD;
            int d    = rem - head * HD;
            float* dst = C + (size_t)part * QKV_STRIDE + (size_t)head * SEQL * HD + d;
#pragma unroll
            for (int fm = 0; fm < 4; ++fm) {
#pragma unroll
                for (int q = 0; q < 4; ++q) {
                    int m = m0 + wm + fm * 16 + lg * 4 + q;
                    dst[(size_t)m * HD] = acc[fm][fn][q] + bcol;
                }
            }
        }
    }
}

// ---------------------------------------------------------------------------
// bf16x3 split MFMA GEMM, HOISTED variant with global_load_lds staging:
// single 32KB LDS buffer (round-6 structure, measured 76.8us), but staging is
// async global->LDS DMA: no VGPR round-trip, no staging VALU. LDS dest is
// LINEAR (HW: wave base + lane*16B); the XOR block-swizzle is applied to the
// GLOBAL source address instead (b ^= r&3, an involution), so LDS contents
// are bit-identical to the validated layout; fragment reads unchanged.
// ---------------------------------------------------------------------------
template <int MODE>
__global__ __launch_bounds__(256) void gemm_mfma_pre_kernel(
    const unsigned short* __restrict__ Ah, const unsigned short* __restrict__ Al,
    const unsigned short* __restrict__ Bh, const unsigned short* __restrict__ Bl,
    const float* __restrict__ bias, float* __restrict__ C,
    int M, int N, int K)
{
    __shared__ unsigned short As[2 * 128 * 32];   // hi plane | lo plane, 16 KB
    __shared__ unsigned short Bs[2 * 128 * 32];   // 16 KB

    const int tid  = threadIdx.x;
    const int m0   = blockIdx.y * 128;
    const int n0   = blockIdx.x * 128;
    const int wave = tid >> 6;
    const int lane = tid & 63;
    const int wm   = (wave >> 1) * 64;
    const int wn   = (wave & 1) * 64;
    const int lrow = lane & 15;
    const int lg   = lane >> 4;          // k-group 0..3

    f32x4 acc[4][4];
#pragma unroll
    for (int i = 0; i < 4; ++i)
#pragma unroll
        for (int j = 0; j < 4; ++j) acc[i][j] = (f32x4){0.f, 0.f, 0.f, 0.f};

    // staging geometry (constant across K-steps):
    // id = l*256 + tid -> r = id>>2 (row 0..127), b = id&3 (16B block 0..3)
    // source block pre-swizzled: bsw = b ^ (r&3); LDS dest linear at id*16B.
    const int r0s = tid >> 2;
    const int r1s = (256 + tid) >> 2;
    const int b0  = tid & 3;
    const int bs0 = b0 ^ (r0s & 3);
    const int bs1 = b0 ^ (r1s & 3);
    const size_t ga0 = (size_t)(m0 + r0s) * K + bs0 * 8;
    const size_t ga1 = (size_t)(m0 + r1s) * K + bs1 * 8;
    const size_t gb0 = (size_t)(n0 + r0s) * K + bs0 * 8;
    const size_t gb1 = (size_t)(n0 + r1s) * K + bs1 * 8;
    unsigned short* ldsA0 = &As[(tid & ~63) * 8];           // wave-uniform bases
    unsigned short* ldsA1 = &As[(256 + (tid & ~63)) * 8];
    unsigned short* ldsB0 = &Bs[(tid & ~63) * 8];
    unsigned short* ldsB1 = &Bs[(256 + (tid & ~63)) * 8];

    for (int k0 = 0; k0 < K; k0 += 32) {
        // ---- async stage tile k0 (8 x 16B per thread, direct to LDS)
        GLD16(Ah + ga0 + k0, ldsA0);
        GLD16(Ah + ga1 + k0, ldsA1);
        GLD16(Al + ga0 + k0, ldsA0 + 4096);
        GLD16(Al + ga1 + k0, ldsA1 + 4096);
        GLD16(Bh + gb0 + k0, ldsB0);
        GLD16(Bh + gb1 + k0, ldsB1);
        GLD16(Bl + gb0 + k0, ldsB0 + 4096);
        GLD16(Bl + gb1 + k0, ldsB1 + 4096);
        __syncthreads();   // compiler drains vmcnt before barrier -> LDS ready

        // ---- fragment reads (swizzled) + MFMA (hi*hi + hi*lo + lo*hi)
        short8v bh[4], bl[4];
#pragma unroll
        for (int fn = 0; fn < 4; ++fn) {
            int row = wn + fn * 16 + lrow;
            int idx = row * 32 + ((lg ^ (row & 3)) << 3);
            bh[fn] = *reinterpret_cast<const short8v*>(&Bs[idx]);
            bl[fn] = *reinterpret_cast<const short8v*>(&Bs[4096 + idx]);
        }
#pragma unroll
        for (int fm = 0; fm < 4; ++fm) {
            int row = wm + fm * 16 + lrow;
            int idx = row * 32 + ((lg ^ (row & 3)) << 3);
            short8v ah = *reinterpret_cast<const short8v*>(&As[idx]);
            short8v al = *reinterpret_cast<const short8v*>(&As[4096 + idx]);
#pragma unroll
            for (int fn = 0; fn < 4; ++fn) {
                acc[fm][fn] = __builtin_amdgcn_mfma_f32_16x16x32_bf16(ah, bh[fn], acc[fm][fn], 0, 0, 0);
                acc[fm][fn] = __builtin_amdgcn_mfma_f32_16x16x32_bf16(ah, bl[fn], acc[fm][fn], 0, 0, 0);
                acc[fm][fn] = __builtin_amdgcn_mfma_f32_16x16x32_bf16(al, bh[fn], acc[fm][fn], 0, 0, 0);
            }
        }
        __syncthreads();   // all reads done before next tile overwrites LDS
    }

#pragma unroll
    for (int fn = 0; fn < 4; ++fn) {
        int n = n0 + wn + fn * 16 + lrow;
        float bcol = bias[n];
        if (MODE == 0) {
#pragma unroll
            for (int fm = 0; fm < 4; ++fm) {
#pragma unroll
                for (int q = 0; q < 4; ++q) {
                    int m = m0 + wm + fm * 16 + lg * 4 + q;
                    C[(size_t)m * N + n] = acc[fm][fn][q] + bcol;
                }
            }
        } else {
            int part = n / EMBED;
            int rem  = n - part * EMBED;
            int head = rem / HD;
            int d    = rem - head * HD;
            float* dst = C + (size_t)part * QKV_STRIDE + (size_t)head * SEQL * HD + d;
#pragma unroll
            for (int fm = 0; fm < 4; ++fm) {
#pragma unroll
                for (int q = 0; q < 4; ++q) {
                    int m = m0 + wm + fm * 16 + lg * 4 + q;
                    dst[(size_t)m * HD] = acc[fm][fn][q] + bcol;
                }
            }
        }
    }
}

// ---------------------------------------------------------------------------
// Rotary (in-place on Q and K, [head][seq][dim] layout) — unchanged
// ---------------------------------------------------------------------------
__global__ __launch_bounds__(256) void rotary_kernel(
    float* __restrict__ Q, float* __restrict__ K, const float* __restrict__ rpe)
{
    int idx = blockIdx.x * 256 + threadIdx.x;
    int r = idx % ROT;
    int s = (idx / ROT) & (SEQL - 1);
    int h = (idx / (ROT * SEQL)) & (NHEAD - 1);
    float* buf = (idx >= NHEAD * SEQL * ROT) ? K : Q;
    float* p = buf + ((size_t)h * SEQL + s) * HD;
    float ang = rpe[s * ROT + r];
    float c = cosf(ang), sn = sinf(ang);
    float t1 = p[r], t2 = p[r + ROT];
    p[r]       = t1 * c - t2 * sn;
    p[r + ROT] = t2 * c + t1 * sn;
}

// ---------------------------------------------------------------------------
// MFMA flash attention — body byte-identical to round 4 (validated absmax
// 9.8e-4). PLANES=1: epilogue writes ctx as bf16 hi/lo planes.
// ---------------------------------------------------------------------------
#define KSTR 104
#define VSTR 72
#define PSTR 72

template <int PLANES>
__global__ __launch_bounds__(256) void attn_mfma_kernel(
    const float* __restrict__ Qb, const float* __restrict__ Kb,
    const float* __restrict__ Vb, const int* __restrict__ cu, int nseg,
    float* __restrict__ ctx, unsigned short* __restrict__ ctxh,
    unsigned short* __restrict__ ctxl)
{
    __shared__ unsigned short kv_hi[64 * KSTR];   // K: [key][104] | V: [d][72]
    __shared__ unsigned short kv_lo[64 * KSTR];
    __shared__ unsigned short p_hi[64 * PSTR];
    __shared__ unsigned short p_lo[64 * PSTR];

    const int tid  = threadIdx.x;
    const int lane = tid & 63;
    const int wave = tid >> 6;
    const int lg   = lane >> 4;        // 0..3
    const int col  = lane & 15;
    const int h    = blockIdx.y;
    const int r0   = blockIdx.x * 64;
    const int wrow = wave * 16;

    // --- segment bounds: exact searchsorted(cu[1:], pos, 'right') semantics
    int qstart[4], qend[4];
#pragma unroll
    for (int q = 0; q < 4; ++q) {
        int row = r0 + wrow + lg * 4 + q;
        int sid = 0;
        for (int i = 1; i <= nseg; ++i) sid += (cu[i] <= row);
        qstart[q] = (sid == 0) ? 0 : cu[sid];
        qend[q]   = (sid >= nseg) ? SEQL : cu[sid + 1];
    }
    int blo, bhi;
    {
        int sid = 0;
        for (int i = 1; i <= nseg; ++i) sid += (cu[i] <= r0);
        blo = (sid == 0) ? 0 : cu[sid];
        sid = 0;
        for (int i = 1; i <= nseg; ++i) sid += (cu[i] <= r0 + 63);
        bhi = (sid >= nseg) ? SEQL : cu[sid + 1];
    }

    // --- Q fragments: A-row = col (wave's row wrow+col), k padded to 96
    const float scale = 0.11180339887498949f;   // 1/sqrt(80)
    short8v qh[3], qlo[3];
    {
        const float* Qr = Qb + ((size_t)h * SEQL + r0 + wrow + col) * HD;
#pragma unroll
        for (int kc = 0; kc < 3; ++kc) {
            int d0 = kc * 32 + lg * 8;
            float v[8];
            if (d0 < HD) {
                float4 f0 = *reinterpret_cast<const float4*>(&Qr[d0]);
                float4 f1 = *reinterpret_cast<const float4*>(&Qr[d0 + 4]);
                v[0] = f0.x * scale; v[1] = f0.y * scale; v[2] = f0.z * scale; v[3] = f0.w * scale;
                v[4] = f1.x * scale; v[5] = f1.y * scale; v[6] = f1.z * scale; v[7] = f1.w * scale;
            } else {
#pragma unroll
                for (int j = 0; j < 8; ++j) v[j] = 0.f;
            }
            short8v hh, ll;
#pragma unroll
            for (int j = 0; j < 8; ++j) {
                unsigned short hb = f2bf(v[j]);
                hh[j] = (short)hb;
                ll[j] = (short)f2bf(v[j] - bf2f(hb));
            }
            qh[kc] = hh; qlo[kc] = ll;
        }
    }

    f32x4 oacc[5];
#pragma unroll
    for (int fn = 0; fn < 5; ++fn) oacc[fn] = (f32x4){0.f, 0.f, 0.f, 0.f};
    float mrun[4] = {-1e30f, -1e30f, -1e30f, -1e30f};
    float lrun[4] = {0.f, 0.f, 0.f, 0.f};

    const float* Kh = Kb + (size_t)h * SEQL * HD;
    const float* Vh = Vb + (size_t)h * SEQL * HD;

    for (int kb = (blo & ~63); kb < bhi; kb += 64) {
        __syncthreads();                 // prior PV reads of kv/pbuf done

        // ---- stage K tile hi/lo: [key][KSTR], coalesced reads
        const float* Kt = Kh + (size_t)kb * HD;
#pragma unroll
        for (int l = 0; l < 5; ++l) {
            int idx = tid + l * 256;     // 64 keys x 20 float4
            int ky = idx / 20, fc = idx % 20;
            float4 f = *reinterpret_cast<const float4*>(&Kt[ky * HD + fc * 4]);
            int base = ky * KSTR + fc * 4;
            unsigned short h0 = f2bf(f.x), h1 = f2bf(f.y), h2 = f2bf(f.z), h3 = f2bf(f.w);
            uint2 w;
            w.x = (unsigned)h0 | ((unsigned)h1 << 16); w.y = (unsigned)h2 | ((unsigned)h3 << 16);
            *reinterpret_cast<uint2*>(&kv_hi[base]) = w;
            h0 = f2bf(f.x - bf2f(h0)); h1 = f2bf(f.y - bf2f(h1));
            h2 = f2bf(f.z - bf2f(h2)); h3 = f2bf(f.w - bf2f(h3));
            w.x = (unsigned)h0 | ((unsigned)h1 << 16); w.y = (unsigned)h2 | ((unsigned)h3 << 16);
            *reinterpret_cast<uint2*>(&kv_lo[base]) = w;
        }
        {   // zero-fill dims 80..95 (both planes)
            int ky = tid >> 2, off = (tid & 3) << 2;
            uint2 z; z.x = 0u; z.y = 0u;
            *reinterpret_cast<uint2*>(&kv_hi[ky * KSTR + 80 + off]) = z;
            *reinterpret_cast<uint2*>(&kv_lo[ky * KSTR + 80 + off]) = z;
        }
        __syncthreads();

        // ---- QK^T: S fragments (col=key, row=lg*4+q)
        f32x4 sfr[4];
#pragma unroll
        for (int kt = 0; kt < 4; ++kt) {
            f32x4 s = (f32x4){0.f, 0.f, 0.f, 0.f};
#pragma unroll
            for (int kc = 0; kc < 3; ++kc) {
                int bidx = (kt * 16 + col) * KSTR + kc * 32 + lg * 8;
                short8v kh = *reinterpret_cast<const short8v*>(&kv_hi[bidx]);
                short8v kl = *reinterpret_cast<const short8v*>(&kv_lo[bidx]);
                s = __builtin_amdgcn_mfma_f32_16x16x32_bf16(qh[kc],  kh, s, 0, 0, 0);
                s = __builtin_amdgcn_mfma_f32_16x16x32_bf16(qlo[kc], kh, s, 0, 0, 0);
                s = __builtin_amdgcn_mfma_f32_16x16x32_bf16(qh[kc],  kl, s, 0, 0, 0);
            }
            sfr[kt] = s;
        }
        __syncthreads();                 // all K reads done -> kv free for V

        // ---- issue V global loads early (latency hides under softmax VALU)
        const float* Vt = Vh + (size_t)kb * HD;
        float4 vreg[5];
#pragma unroll
        for (int l = 0; l < 5; ++l) {
            int idx = tid + l * 256;     // d-major: fc = idx/64, ky = idx%64
            int fc = idx >> 6, ky = idx & 63;
            vreg[l] = *reinterpret_cast<const float4*>(&Vt[ky * HD + fc * 4]);
        }

        // ---- online softmax (per q-row; row spread over 16 lanes x 4 kt)
#pragma unroll
        for (int q = 0; q < 4; ++q) {
            float sv[4];
            float mx = -1e30f;
#pragma unroll
            for (int kt = 0; kt < 4; ++kt) {
                int key = kb + kt * 16 + col;
                bool ok = (key >= qstart[q]) && (key < qend[q]);
                sv[kt] = ok ? sfr[kt][q] : -1e30f;
                mx = fmaxf(mx, sv[kt]);
            }
            mx = fmaxf(mx, __shfl_xor(mx, 1));
            mx = fmaxf(mx, __shfl_xor(mx, 2));
            mx = fmaxf(mx, __shfl_xor(mx, 4));
            mx = fmaxf(mx, __shfl_xor(mx, 8));
            float mnew  = fmaxf(mrun[q], mx);
            float alpha = __expf(mrun[q] - mnew);
            float ps = 0.f;
            int prow = (wrow + lg * 4 + q) * PSTR;
#pragma unroll
            for (int kt = 0; kt < 4; ++kt) {
                float p = (sv[kt] > -1e29f) ? __expf(sv[kt] - mnew) : 0.f;
                ps += p;
                unsigned short ph = f2bf(p);
                p_hi[prow + kt * 16 + col] = ph;
                p_lo[prow + kt * 16 + col] = f2bf(p - bf2f(ph));
            }
            ps += __shfl_xor(ps, 1);
            ps += __shfl_xor(ps, 2);
            ps += __shfl_xor(ps, 4);
            ps += __shfl_xor(ps, 8);
            lrun[q] = lrun[q] * alpha + ps;
            mrun[q] = mnew;
#pragma unroll
            for (int fn = 0; fn < 5; ++fn) oacc[fn][q] *= alpha;
        }

        // ---- write V^T to LDS [d][VSTR] (conflict-free: ky fast-varying)
#pragma unroll
        for (int l = 0; l < 5; ++l) {
            int idx = tid + l * 256;
            int fc = idx >> 6, ky = idx & 63;
            float4 f = vreg[l];
            float vv[4] = {f.x, f.y, f.z, f.w};
#pragma unroll
            for (int e = 0; e < 4; ++e) {
                unsigned short hb = f2bf(vv[e]);
                kv_hi[(fc * 4 + e) * VSTR + ky] = hb;
                kv_lo[(fc * 4 + e) * VSTR + ky] = f2bf(vv[e] - bf2f(hb));
            }
        }
        __syncthreads();                 // V + P ready

        // ---- PV: O += P * V   (A=P rows, B=V^T cols=d, k=keys)
#pragma unroll
        for (int kc2 = 0; kc2 < 2; ++kc2) {
            int aidx = (wrow + col) * PSTR + kc2 * 32 + lg * 8;
            short8v pah = *reinterpret_cast<const short8v*>(&p_hi[aidx]);
            short8v pal = *reinterpret_cast<const short8v*>(&p_lo[aidx]);
#pragma unroll
            for (int fn = 0; fn < 5; ++fn) {
                int bidx = (fn * 16 + col) * VSTR + kc2 * 32 + lg * 8;
                short8v vh = *reinterpret_cast<const short8v*>(&kv_hi[bidx]);
                short8v vl = *reinterpret_cast<const short8v*>(&kv_lo[bidx]);
                oacc[fn] = __builtin_amdgcn_mfma_f32_16x16x32_bf16(pah, vh, oacc[fn], 0, 0, 0);
                oacc[fn] = __builtin_amdgcn_mfma_f32_16x16x32_bf16(pal, vh, oacc[fn], 0, 0, 0);
                oacc[fn] = __builtin_amdgcn_mfma_f32_16x16x32_bf16(pah, vl, oacc[fn], 0, 0, 0);
            }
        }
    }

    // ---- epilogue: ctx[row][h*80 + d] = O/l (fp32 or bf16 hi/lo planes)
#pragma unroll
    for (int q = 0; q < 4; ++q) {
        float inv = 1.f / lrun[q];
        size_t rowoff = (size_t)(r0 + wrow + lg * 4 + q) * EMBED + h * HD;
        if (PLANES) {
#pragma unroll
            for (int fn = 0; fn < 5; ++fn) {
                float val = oacc[fn][q] * inv;
                unsigned short hb = f2bf(val);
                ctxh[rowoff + fn * 16 + col] = hb;
                ctxl[rowoff + fn * 16 + col] = f2bf(val - bf2f(hb));
            }
        } else {
#pragma unroll
            for (int fn = 0; fn < 5; ++fn)
                ctx[rowoff + fn * 16 + col] = oacc[fn][q] * inv;
        }
    }
}

// ---------------------------------------------------------------------------
extern "C" void kernel_launch(void* const* d_in, const int* in_sizes, int n_in,
                              void* d_out, int out_size, void* d_ws, size_t ws_size,
                              hipStream_t stream)
{
    const float* x      = (const float*)d_in[0];
    const float* rpe    = (const float*)d_in[1];
    const int*   cu     = (const int*)d_in[2];
    // d_in[3] = max_seqlen (unused)
    const float* qkv_w  = (const float*)d_in[4];
    const float* qkv_b  = (const float*)d_in[5];
    const float* proj_w = (const float*)d_in[6];
    const float* proj_b = (const float*)d_in[7];

    float* ws  = (float*)d_ws;
    float* Q   = ws;                                 // R0: fp32 2.62M
    float* K   = ws + (size_t)QKV_STRIDE;            // R1
    float* V   = ws + (size_t)2 * QKV_STRIDE;        // R2
    float* ctx = ws + (size_t)3 * QKV_STRIDE;        // R3 (10.5MB)

    const int nseg = in_sizes[2] - 1;

    // Hoisted path needs R3 (x planes) + R4 (w planes, later ctx planes)
    // + R5 (proj_w planes): 68,157,440 bytes total. (Proven present.)
    const bool HOIST = ws_size >= 68157440ULL;

    if (HOIST) {
        unsigned short* xh   = (unsigned short*)(ws + (size_t)3 * QKV_STRIDE);    // R3
        unsigned short* xl   = xh + (size_t)SEQL * EMBED;
        unsigned short* wh   = (unsigned short*)(ws + (size_t)4 * QKV_STRIDE);    // R4
        unsigned short* wl   = wh + (size_t)QKV_N * EMBED;
        unsigned short* ctxh = (unsigned short*)(ws + (size_t)4 * QKV_STRIDE);    // overlays wh/wl
        unsigned short* ctxl = ctxh + (size_t)SEQL * EMBED;
        unsigned short* ph   = (unsigned short*)((char*)d_ws + 61603840);         // R5
        unsigned short* pl   = ph + (size_t)EMBED * EMBED;

        const int c0 = SEQL * EMBED / 4, c1 = QKV_N * EMBED / 4, c2 = EMBED * EMBED / 4;

        // 0) pre-split all three operands (one launch)
        split3_kernel<<<(c0 + c1 + c2 + 255) / 256, 256, 0, stream>>>(
            x, xh, xl, c0, qkv_w, wh, wl, c1, proj_w, ph, pl, c2);

        // 1) QKV projection (global_load_lds staging) -> Q/K/V [head][seq][dim]
        gemm_mfma_pre_kernel<1><<<dim3(QKV_N / 128, SEQL / 128), 256, 0, stream>>>(
            xh, xl, wh, wl, qkv_b, Q, SEQL, QKV_N, EMBED);

        // 2) rotary on Q,K in place
        rotary_kernel<<<(2 * NHEAD * SEQL * ROT) / 256, 256, 0, stream>>>(Q, K, rpe);

        // 3) attention -> ctx planes directly (w planes dead by now)
        attn_mfma_kernel<1><<<dim3(SEQL / 64, NHEAD), 256, 0, stream>>>(
            Q, K, V, cu, nseg, nullptr, ctxh, ctxl);

        // 4) output projection (global_load_lds staging)
        gemm_mfma_pre_kernel<0><<<dim3(EMBED / 128, SEQL / 128), 256, 0, stream>>>(
            ctxh, ctxl, ph, pl, proj_b, (float*)d_out, SEQL, EMBED, EMBED);
    } else {
        // fallback: fully-validated round-3 pipeline with round-4 attention
        gemm_mfma_kernel<1><<<dim3(QKV_N / 128, SEQL / 128), 256, 0, stream>>>(
            x, qkv_w, qkv_b, Q, SEQL, QKV_N, EMBED);
        rotary_kernel<<<(2 * NHEAD * SEQL * ROT) / 256, 256, 0, stream>>>(Q, K, rpe);
        attn_mfma_kernel<0><<<dim3(SEQL / 64, NHEAD), 256, 0, stream>>>(
            Q, K, V, cu, nseg, ctx, nullptr, nullptr);
        gemm_mfma_kernel<0><<<dim3(EMBED / 128, SEQL / 128), 256, 0, stream>>>(
            ctx, proj_w, proj_b, (float*)d_out, SEQL, EMBED, EMBED);
    }
}

// Round 11
// 275.472 us; speedup vs baseline: 1.0851x; 1.0082x over previous
//
#include <hip/hip_runtime.h>
#include <hip/hip_bf16.h>
#include <cstdint>
#include <cstddef>

#define EMBED 1280
#define NHEAD 16
#define HD 80
#define ROT 40
#define SEQL 2048
#define QKV_N 3840
#define QKV_STRIDE (NHEAD * SEQL * HD)   // elems per Q/K/V buffer = 2,621,440

typedef __attribute__((ext_vector_type(8))) short short8v;  // 8 bf16 (4 VGPRs)
typedef __attribute__((ext_vector_type(4))) short short4v;  // 4 bf16 (8B)
typedef __attribute__((ext_vector_type(4))) float f32x4;    // MFMA accumulator

__device__ inline unsigned short f2bf(float f) {            // RNE float->bf16
    unsigned u = __float_as_uint(f);
    u += 0x7FFFu + ((u >> 16) & 1u);
    return (unsigned short)(u >> 16);
}
__device__ inline float bf2f(unsigned short h) {
    return __uint_as_float(((unsigned)h) << 16);
}

// 16B async global->LDS (linear dest = wave base + lane*16; size literal 16)
#define GLD16(GP, LP)                                                         \
    __builtin_amdgcn_global_load_lds(                                         \
        (const __attribute__((address_space(1))) unsigned int*)(GP),          \
        (__attribute__((address_space(3))) unsigned int*)(LP), 16, 0, 0)

// ---------------------------------------------------------------------------
// Fused fp32 -> bf16 hi/lo split for the 3 GEMM operands (1 launch)
// ---------------------------------------------------------------------------
__global__ __launch_bounds__(256) void split3_kernel(
    const float* __restrict__ s0, unsigned short* __restrict__ h0, unsigned short* __restrict__ l0, int c0,
    const float* __restrict__ s1, unsigned short* __restrict__ h1, unsigned short* __restrict__ l1, int c1,
    const float* __restrict__ s2, unsigned short* __restrict__ h2, unsigned short* __restrict__ l2, int c2)
{
    int i = blockIdx.x * 256 + threadIdx.x;
    const float* s; unsigned short *hp, *lp; int base;
    if (i < c0)               { s = s0; hp = h0; lp = l0; base = i; }
    else if (i < c0 + c1)     { s = s1; hp = h1; lp = l1; base = i - c0; }
    else if (i < c0 + c1 + c2){ s = s2; hp = h2; lp = l2; base = i - c0 - c1; }
    else return;
    float4 v = reinterpret_cast<const float4*>(s)[base];
    unsigned short a0 = f2bf(v.x), a1 = f2bf(v.y), a2 = f2bf(v.z), a3 = f2bf(v.w);
    short4v hv, lv;
    hv[0] = (short)a0; hv[1] = (short)a1; hv[2] = (short)a2; hv[3] = (short)a3;
    lv[0] = (short)f2bf(v.x - bf2f(a0));
    lv[1] = (short)f2bf(v.y - bf2f(a1));
    lv[2] = (short)f2bf(v.z - bf2f(a2));
    lv[3] = (short)f2bf(v.w - bf2f(a3));
    *reinterpret_cast<short4v*>(&hp[base * 4]) = hv;
    *reinterpret_cast<short4v*>(&lp[base * 4]) = lv;
}

// ---------------------------------------------------------------------------
// bf16x3 split MFMA GEMM, FALLBACK variant (validated round 3; in-loop conv)
// ---------------------------------------------------------------------------
template <int MODE>
__global__ __launch_bounds__(256) void gemm_mfma_kernel(
    const float* __restrict__ A, const float* __restrict__ B,
    const float* __restrict__ bias, float* __restrict__ C,
    int M, int N, int K)
{
    __shared__ unsigned short As[2 * 128 * 32];   // 16 KB
    __shared__ unsigned short Bs[2 * 128 * 32];   // 16 KB

    const int tid  = threadIdx.x;
    const int m0   = blockIdx.y * 128;
    const int n0   = blockIdx.x * 128;
    const int wave = tid >> 6;
    const int lane = tid & 63;
    const int wm   = (wave >> 1) * 64;
    const int wn   = (wave & 1) * 64;
    const int lrow = lane & 15;
    const int lg   = lane >> 4;          // k-group 0..3

    f32x4 acc[4][4];
#pragma unroll
    for (int i = 0; i < 4; ++i)
#pragma unroll
        for (int j = 0; j < 4; ++j) acc[i][j] = (f32x4){0.f, 0.f, 0.f, 0.f};

    for (int k0 = 0; k0 < K; k0 += 32) {
        float4 ar[4], br[4];
#pragma unroll
        for (int l = 0; l < 4; ++l) {
            int id = l * 256 + tid;          // 0..1023 = 128 rows x 8 float4
            int r = id >> 3, c = id & 7;
            ar[l] = *reinterpret_cast<const float4*>(&A[(size_t)(m0 + r) * K + k0 + c * 4]);
            br[l] = *reinterpret_cast<const float4*>(&B[(size_t)(n0 + r) * K + k0 + c * 4]);
        }
        __syncthreads();
#pragma unroll
        for (int l = 0; l < 4; ++l) {
            int id = l * 256 + tid;
            int r = id >> 3, c = id & 7;
            int base = r * 32 + (((c >> 1) ^ (r & 3)) << 3) + ((c & 1) << 2);
            float4 v = ar[l];
            unsigned short h0 = f2bf(v.x), h1 = f2bf(v.y), h2 = f2bf(v.z), h3 = f2bf(v.w);
            unsigned short g0 = f2bf(v.x - bf2f(h0)), g1 = f2bf(v.y - bf2f(h1));
            unsigned short g2 = f2bf(v.z - bf2f(h2)), g3 = f2bf(v.w - bf2f(h3));
            uint2 w;
            w.x = (unsigned)h0 | ((unsigned)h1 << 16); w.y = (unsigned)h2 | ((unsigned)h3 << 16);
            *reinterpret_cast<uint2*>(&As[base]) = w;
            w.x = (unsigned)g0 | ((unsigned)g1 << 16); w.y = (unsigned)g2 | ((unsigned)g3 << 16);
            *reinterpret_cast<uint2*>(&As[4096 + base]) = w;
            v = br[l];
            h0 = f2bf(v.x); h1 = f2bf(v.y); h2 = f2bf(v.z); h3 = f2bf(v.w);
            g0 = f2bf(v.x - bf2f(h0)); g1 = f2bf(v.y - bf2f(h1));
            g2 = f2bf(v.z - bf2f(h2)); g3 = f2bf(v.w - bf2f(h3));
            w.x = (unsigned)h0 | ((unsigned)h1 << 16); w.y = (unsigned)h2 | ((unsigned)h3 << 16);
            *reinterpret_cast<uint2*>(&Bs[base]) = w;
            w.x = (unsigned)g0 | ((unsigned)g1 << 16); w.y = (unsigned)g2 | ((unsigned)g3 << 16);
            *reinterpret_cast<uint2*>(&Bs[4096 + base]) = w;
        }
        __syncthreads();
        short8v bh[4], bl[4];
#pragma unroll
        for (int fn = 0; fn < 4; ++fn) {
            int row = wn + fn * 16 + lrow;
            int idx = row * 32 + ((lg ^ (row & 3)) << 3);
            bh[fn] = *reinterpret_cast<const short8v*>(&Bs[idx]);
            bl[fn] = *reinterpret_cast<const short8v*>(&Bs[4096 + idx]);
        }
#pragma unroll
        for (int fm = 0; fm < 4; ++fm) {
            int row = wm + fm * 16 + lrow;
            int idx = row * 32 + ((lg ^ (row & 3)) << 3);
            short8v ah = *reinterpret_cast<const short8v*>(&As[idx]);
            short8v al = *reinterpret_cast<const short8v*>(&As[4096 + idx]);
#pragma unroll
            for (int fn = 0; fn < 4; ++fn) {
                acc[fm][fn] = __builtin_amdgcn_mfma_f32_16x16x32_bf16(ah, bh[fn], acc[fm][fn], 0, 0, 0);
                acc[fm][fn] = __builtin_amdgcn_mfma_f32_16x16x32_bf16(ah, bl[fn], acc[fm][fn], 0, 0, 0);
                acc[fm][fn] = __builtin_amdgcn_mfma_f32_16x16x32_bf16(al, bh[fn], acc[fm][fn], 0, 0, 0);
            }
        }
    }

#pragma unroll
    for (int fn = 0; fn < 4; ++fn) {
        int n = n0 + wn + fn * 16 + lrow;
        float bcol = bias[n];
        if (MODE == 0) {
#pragma unroll
            for (int fm = 0; fm < 4; ++fm) {
#pragma unroll
                for (int q = 0; q < 4; ++q) {
                    int m = m0 + wm + fm * 16 + lg * 4 + q;
                    C[(size_t)m * N + n] = acc[fm][fn][q] + bcol;
                }
            }
        } else {
            int part = n / EMBED;
            int rem  = n - part * EMBED;
            int head = rem / HD;
            int d    = rem - head * HD;
            float* dst = C + (size_t)part * QKV_STRIDE + (size_t)head * SEQL * HD + d;
#pragma unroll
            for (int fm = 0; fm < 4; ++fm) {
#pragma unroll
                for (int q = 0; q < 4; ++q) {
                    int m = m0 + wm + fm * 16 + lg * 4 + q;
                    dst[(size_t)m * HD] = acc[fm][fn][q] + bcol;
                }
            }
        }
    }
}

// ---------------------------------------------------------------------------
// bf16x3 split MFMA GEMM, HOISTED variant: global_load_lds staging into a
// DOUBLE-BUFFERED LDS (2x32KB). Tile t+1's 8 GLD16s are issued BEFORE the
// ds_read+MFMA block on tile t, so their L2/HBM latency hides under compute;
// the single end-of-step __syncthreads() (vmcnt drain) then completes them.
// In-flight data costs ZERO VGPRs (unlike round-9's reg-staged dbuf).
// LDS dest linear (HW requirement); XOR block-swizzle pre-applied to the
// GLOBAL source address (b ^= r&3, involution) -> LDS contents identical to
// the validated layout; fragment reads unchanged.
// ---------------------------------------------------------------------------
template <int MODE>
__global__ __launch_bounds__(256) void gemm_mfma_pre_kernel(
    const unsigned short* __restrict__ Ah, const unsigned short* __restrict__ Al,
    const unsigned short* __restrict__ Bh, const unsigned short* __restrict__ Bl,
    const float* __restrict__ bias, float* __restrict__ C,
    int M, int N, int K)
{
    __shared__ unsigned short As[2][2 * 128 * 32];   // 2 bufs x (hi|lo) 16 KB
    __shared__ unsigned short Bs[2][2 * 128 * 32];   // total 64 KB

    const int tid  = threadIdx.x;
    const int m0   = blockIdx.y * 128;
    const int n0   = blockIdx.x * 128;
    const int wave = tid >> 6;
    const int lane = tid & 63;
    const int wm   = (wave >> 1) * 64;
    const int wn   = (wave & 1) * 64;
    const int lrow = lane & 15;
    const int lg   = lane >> 4;          // k-group 0..3

    f32x4 acc[4][4];
#pragma unroll
    for (int i = 0; i < 4; ++i)
#pragma unroll
        for (int j = 0; j < 4; ++j) acc[i][j] = (f32x4){0.f, 0.f, 0.f, 0.f};

    // staging geometry (constant across K-steps):
    // id = l*256 + tid -> r = id>>2 (row 0..127), b = id&3 (16B block 0..3)
    // source block pre-swizzled: bsw = b ^ (r&3); LDS dest linear at id*16B.
    const int r0s = tid >> 2;
    const int r1s = (256 + tid) >> 2;
    const int b0  = tid & 3;
    const int bs0 = b0 ^ (r0s & 3);
    const int bs1 = b0 ^ (r1s & 3);
    const size_t ga0 = (size_t)(m0 + r0s) * K + bs0 * 8;
    const size_t ga1 = (size_t)(m0 + r1s) * K + bs1 * 8;
    const size_t gb0 = (size_t)(n0 + r0s) * K + bs0 * 8;
    const size_t gb1 = (size_t)(n0 + r1s) * K + bs1 * 8;
    const int lo0 = (tid & ~63) * 8;            // wave-uniform LDS offsets
    const int lo1 = (256 + (tid & ~63)) * 8;

    // prologue: stage tile 0 into buffer 0
    GLD16(Ah + ga0, &As[0][lo0]);
    GLD16(Ah + ga1, &As[0][lo1]);
    GLD16(Al + ga0, &As[0][lo0 + 4096]);
    GLD16(Al + ga1, &As[0][lo1 + 4096]);
    GLD16(Bh + gb0, &Bs[0][lo0]);
    GLD16(Bh + gb1, &Bs[0][lo1]);
    GLD16(Bl + gb0, &Bs[0][lo0 + 4096]);
    GLD16(Bl + gb1, &Bs[0][lo1 + 4096]);
    __syncthreads();

    const int NT = K >> 5;               // 40 for both GEMMs
    for (int t = 0; t < NT; ++t) {
        const int cur = t & 1, nxt = cur ^ 1;
        // ---- issue NEXT tile's loads first (latency hides under MFMA below)
        if (t + 1 < NT) {
            const size_t k1 = (size_t)(t + 1) * 32;
            GLD16(Ah + ga0 + k1, &As[nxt][lo0]);
            GLD16(Ah + ga1 + k1, &As[nxt][lo1]);
            GLD16(Al + ga0 + k1, &As[nxt][lo0 + 4096]);
            GLD16(Al + ga1 + k1, &As[nxt][lo1 + 4096]);
            GLD16(Bh + gb0 + k1, &Bs[nxt][lo0]);
            GLD16(Bh + gb1 + k1, &Bs[nxt][lo1]);
            GLD16(Bl + gb0 + k1, &Bs[nxt][lo0 + 4096]);
            GLD16(Bl + gb1 + k1, &Bs[nxt][lo1 + 4096]);
        }
        // ---- fragment reads (swizzled) + MFMA on current buffer
        short8v bh[4], bl[4];
#pragma unroll
        for (int fn = 0; fn < 4; ++fn) {
            int row = wn + fn * 16 + lrow;
            int idx = row * 32 + ((lg ^ (row & 3)) << 3);
            bh[fn] = *reinterpret_cast<const short8v*>(&Bs[cur][idx]);
            bl[fn] = *reinterpret_cast<const short8v*>(&Bs[cur][4096 + idx]);
        }
#pragma unroll
        for (int fm = 0; fm < 4; ++fm) {
            int row = wm + fm * 16 + lrow;
            int idx = row * 32 + ((lg ^ (row & 3)) << 3);
            short8v ah = *reinterpret_cast<const short8v*>(&As[cur][idx]);
            short8v al = *reinterpret_cast<const short8v*>(&As[cur][4096 + idx]);
#pragma unroll
            for (int fn = 0; fn < 4; ++fn) {
                acc[fm][fn] = __builtin_amdgcn_mfma_f32_16x16x32_bf16(ah, bh[fn], acc[fm][fn], 0, 0, 0);
                acc[fm][fn] = __builtin_amdgcn_mfma_f32_16x16x32_bf16(ah, bl[fn], acc[fm][fn], 0, 0, 0);
                acc[fm][fn] = __builtin_amdgcn_mfma_f32_16x16x32_bf16(al, bh[fn], acc[fm][fn], 0, 0, 0);
            }
        }
        // one barrier per K-step: publishes buf[nxt] (vmcnt drain) and
        // retires buf[cur] reads before it is overwritten at t+2.
        __syncthreads();
    }

#pragma unroll
    for (int fn = 0; fn < 4; ++fn) {
        int n = n0 + wn + fn * 16 + lrow;
        float bcol = bias[n];
        if (MODE == 0) {
#pragma unroll
            for (int fm = 0; fm < 4; ++fm) {
#pragma unroll
                for (int q = 0; q < 4; ++q) {
                    int m = m0 + wm + fm * 16 + lg * 4 + q;
                    C[(size_t)m * N + n] = acc[fm][fn][q] + bcol;
                }
            }
        } else {
            int part = n / EMBED;
            int rem  = n - part * EMBED;
            int head = rem / HD;
            int d    = rem - head * HD;
            float* dst = C + (size_t)part * QKV_STRIDE + (size_t)head * SEQL * HD + d;
#pragma unroll
            for (int fm = 0; fm < 4; ++fm) {
#pragma unroll
                for (int q = 0; q < 4; ++q) {
                    int m = m0 + wm + fm * 16 + lg * 4 + q;
                    dst[(size_t)m * HD] = acc[fm][fn][q] + bcol;
                }
            }
        }
    }
}

// ---------------------------------------------------------------------------
// Rotary (in-place on Q and K, [head][seq][dim] layout) — unchanged
// ---------------------------------------------------------------------------
__global__ __launch_bounds__(256) void rotary_kernel(
    float* __restrict__ Q, float* __restrict__ K, const float* __restrict__ rpe)
{
    int idx = blockIdx.x * 256 + threadIdx.x;
    int r = idx % ROT;
    int s = (idx / ROT) & (SEQL - 1);
    int h = (idx / (ROT * SEQL)) & (NHEAD - 1);
    float* buf = (idx >= NHEAD * SEQL * ROT) ? K : Q;
    float* p = buf + ((size_t)h * SEQL + s) * HD;
    float ang = rpe[s * ROT + r];
    float c = cosf(ang), sn = sinf(ang);
    float t1 = p[r], t2 = p[r + ROT];
    p[r]       = t1 * c - t2 * sn;
    p[r + ROT] = t2 * c + t1 * sn;
}

// ---------------------------------------------------------------------------
// MFMA flash attention — body byte-identical to round 4 (validated absmax
// 9.8e-4). PLANES=1: epilogue writes ctx as bf16 hi/lo planes.
// ---------------------------------------------------------------------------
#define KSTR 104
#define VSTR 72
#define PSTR 72

template <int PLANES>
__global__ __launch_bounds__(256) void attn_mfma_kernel(
    const float* __restrict__ Qb, const float* __restrict__ Kb,
    const float* __restrict__ Vb, const int* __restrict__ cu, int nseg,
    float* __restrict__ ctx, unsigned short* __restrict__ ctxh,
    unsigned short* __restrict__ ctxl)
{
    __shared__ unsigned short kv_hi[64 * KSTR];   // K: [key][104] | V: [d][72]
    __shared__ unsigned short kv_lo[64 * KSTR];
    __shared__ unsigned short p_hi[64 * PSTR];
    __shared__ unsigned short p_lo[64 * PSTR];

    const int tid  = threadIdx.x;
    const int lane = tid & 63;
    const int wave = tid >> 6;
    const int lg   = lane >> 4;        // 0..3
    const int col  = lane & 15;
    const int h    = blockIdx.y;
    const int r0   = blockIdx.x * 64;
    const int wrow = wave * 16;

    // --- segment bounds: exact searchsorted(cu[1:], pos, 'right') semantics
    int qstart[4], qend[4];
#pragma unroll
    for (int q = 0; q < 4; ++q) {
        int row = r0 + wrow + lg * 4 + q;
        int sid = 0;
        for (int i = 1; i <= nseg; ++i) sid += (cu[i] <= row);
        qstart[q] = (sid == 0) ? 0 : cu[sid];
        qend[q]   = (sid >= nseg) ? SEQL : cu[sid + 1];
    }
    int blo, bhi;
    {
        int sid = 0;
        for (int i = 1; i <= nseg; ++i) sid += (cu[i] <= r0);
        blo = (sid == 0) ? 0 : cu[sid];
        sid = 0;
        for (int i = 1; i <= nseg; ++i) sid += (cu[i] <= r0 + 63);
        bhi = (sid >= nseg) ? SEQL : cu[sid + 1];
    }

    // --- Q fragments: A-row = col (wave's row wrow+col), k padded to 96
    const float scale = 0.11180339887498949f;   // 1/sqrt(80)
    short8v qh[3], qlo[3];
    {
        const float* Qr = Qb + ((size_t)h * SEQL + r0 + wrow + col) * HD;
#pragma unroll
        for (int kc = 0; kc < 3; ++kc) {
            int d0 = kc * 32 + lg * 8;
            float v[8];
            if (d0 < HD) {
                float4 f0 = *reinterpret_cast<const float4*>(&Qr[d0]);
                float4 f1 = *reinterpret_cast<const float4*>(&Qr[d0 + 4]);
                v[0] = f0.x * scale; v[1] = f0.y * scale; v[2] = f0.z * scale; v[3] = f0.w * scale;
                v[4] = f1.x * scale; v[5] = f1.y * scale; v[6] = f1.z * scale; v[7] = f1.w * scale;
            } else {
#pragma unroll
                for (int j = 0; j < 8; ++j) v[j] = 0.f;
            }
            short8v hh, ll;
#pragma unroll
            for (int j = 0; j < 8; ++j) {
                unsigned short hb = f2bf(v[j]);
                hh[j] = (short)hb;
                ll[j] = (short)f2bf(v[j] - bf2f(hb));
            }
            qh[kc] = hh; qlo[kc] = ll;
        }
    }

    f32x4 oacc[5];
#pragma unroll
    for (int fn = 0; fn < 5; ++fn) oacc[fn] = (f32x4){0.f, 0.f, 0.f, 0.f};
    float mrun[4] = {-1e30f, -1e30f, -1e30f, -1e30f};
    float lrun[4] = {0.f, 0.f, 0.f, 0.f};

    const float* Kh = Kb + (size_t)h * SEQL * HD;
    const float* Vh = Vb + (size_t)h * SEQL * HD;

    for (int kb = (blo & ~63); kb < bhi; kb += 64) {
        __syncthreads();                 // prior PV reads of kv/pbuf done

        // ---- stage K tile hi/lo: [key][KSTR], coalesced reads
        const float* Kt = Kh + (size_t)kb * HD;
#pragma unroll
        for (int l = 0; l < 5; ++l) {
            int idx = tid + l * 256;     // 64 keys x 20 float4
            int ky = idx / 20, fc = idx % 20;
            float4 f = *reinterpret_cast<const float4*>(&Kt[ky * HD + fc * 4]);
            int base = ky * KSTR + fc * 4;
            unsigned short h0 = f2bf(f.x), h1 = f2bf(f.y), h2 = f2bf(f.z), h3 = f2bf(f.w);
            uint2 w;
            w.x = (unsigned)h0 | ((unsigned)h1 << 16); w.y = (unsigned)h2 | ((unsigned)h3 << 16);
            *reinterpret_cast<uint2*>(&kv_hi[base]) = w;
            h0 = f2bf(f.x - bf2f(h0)); h1 = f2bf(f.y - bf2f(h1));
            h2 = f2bf(f.z - bf2f(h2)); h3 = f2bf(f.w - bf2f(h3));
            w.x = (unsigned)h0 | ((unsigned)h1 << 16); w.y = (unsigned)h2 | ((unsigned)h3 << 16);
            *reinterpret_cast<uint2*>(&kv_lo[base]) = w;
        }
        {   // zero-fill dims 80..95 (both planes)
            int ky = tid >> 2, off = (tid & 3) << 2;
            uint2 z; z.x = 0u; z.y = 0u;
            *reinterpret_cast<uint2*>(&kv_hi[ky * KSTR + 80 + off]) = z;
            *reinterpret_cast<uint2*>(&kv_lo[ky * KSTR + 80 + off]) = z;
        }
        __syncthreads();

        // ---- QK^T: S fragments (col=key, row=lg*4+q)
        f32x4 sfr[4];
#pragma unroll
        for (int kt = 0; kt < 4; ++kt) {
            f32x4 s = (f32x4){0.f, 0.f, 0.f, 0.f};
#pragma unroll
            for (int kc = 0; kc < 3; ++kc) {
                int bidx = (kt * 16 + col) * KSTR + kc * 32 + lg * 8;
                short8v kh = *reinterpret_cast<const short8v*>(&kv_hi[bidx]);
                short8v kl = *reinterpret_cast<const short8v*>(&kv_lo[bidx]);
                s = __builtin_amdgcn_mfma_f32_16x16x32_bf16(qh[kc],  kh, s, 0, 0, 0);
                s = __builtin_amdgcn_mfma_f32_16x16x32_bf16(qlo[kc], kh, s, 0, 0, 0);
                s = __builtin_amdgcn_mfma_f32_16x16x32_bf16(qh[kc],  kl, s, 0, 0, 0);
            }
            sfr[kt] = s;
        }
        __syncthreads();                 // all K reads done -> kv free for V

        // ---- issue V global loads early (latency hides under softmax VALU)
        const float* Vt = Vh + (size_t)kb * HD;
        float4 vreg[5];
#pragma unroll
        for (int l = 0; l < 5; ++l) {
            int idx = tid + l * 256;     // d-major: fc = idx/64, ky = idx%64
            int fc = idx >> 6, ky = idx & 63;
            vreg[l] = *reinterpret_cast<const float4*>(&Vt[ky * HD + fc * 4]);
        }

        // ---- online softmax (per q-row; row spread over 16 lanes x 4 kt)
#pragma unroll
        for (int q = 0; q < 4; ++q) {
            float sv[4];
            float mx = -1e30f;
#pragma unroll
            for (int kt = 0; kt < 4; ++kt) {
                int key = kb + kt * 16 + col;
                bool ok = (key >= qstart[q]) && (key < qend[q]);
                sv[kt] = ok ? sfr[kt][q] : -1e30f;
                mx = fmaxf(mx, sv[kt]);
            }
            mx = fmaxf(mx, __shfl_xor(mx, 1));
            mx = fmaxf(mx, __shfl_xor(mx, 2));
            mx = fmaxf(mx, __shfl_xor(mx, 4));
            mx = fmaxf(mx, __shfl_xor(mx, 8));
            float mnew  = fmaxf(mrun[q], mx);
            float alpha = __expf(mrun[q] - mnew);
            float ps = 0.f;
            int prow = (wrow + lg * 4 + q) * PSTR;
#pragma unroll
            for (int kt = 0; kt < 4; ++kt) {
                float p = (sv[kt] > -1e29f) ? __expf(sv[kt] - mnew) : 0.f;
                ps += p;
                unsigned short ph = f2bf(p);
                p_hi[prow + kt * 16 + col] = ph;
                p_lo[prow + kt * 16 + col] = f2bf(p - bf2f(ph));
            }
            ps += __shfl_xor(ps, 1);
            ps += __shfl_xor(ps, 2);
            ps += __shfl_xor(ps, 4);
            ps += __shfl_xor(ps, 8);
            lrun[q] = lrun[q] * alpha + ps;
            mrun[q] = mnew;
#pragma unroll
            for (int fn = 0; fn < 5; ++fn) oacc[fn][q] *= alpha;
        }

        // ---- write V^T to LDS [d][VSTR] (conflict-free: ky fast-varying)
#pragma unroll
        for (int l = 0; l < 5; ++l) {
            int idx = tid + l * 256;
            int fc = idx >> 6, ky = idx & 63;
            float4 f = vreg[l];
            float vv[4] = {f.x, f.y, f.z, f.w};
#pragma unroll
            for (int e = 0; e < 4; ++e) {
                unsigned short hb = f2bf(vv[e]);
                kv_hi[(fc * 4 + e) * VSTR + ky] = hb;
                kv_lo[(fc * 4 + e) * VSTR + ky] = f2bf(vv[e] - bf2f(hb));
            }
        }
        __syncthreads();                 // V + P ready

        // ---- PV: O += P * V   (A=P rows, B=V^T cols=d, k=keys)
#pragma unroll
        for (int kc2 = 0; kc2 < 2; ++kc2) {
            int aidx = (wrow + col) * PSTR + kc2 * 32 + lg * 8;
            short8v pah = *reinterpret_cast<const short8v*>(&p_hi[aidx]);
            short8v pal = *reinterpret_cast<const short8v*>(&p_lo[aidx]);
#pragma unroll
            for (int fn = 0; fn < 5; ++fn) {
                int bidx = (fn * 16 + col) * VSTR + kc2 * 32 + lg * 8;
                short8v vh = *reinterpret_cast<const short8v*>(&kv_hi[bidx]);
                short8v vl = *reinterpret_cast<const short8v*>(&kv_lo[bidx]);
                oacc[fn] = __builtin_amdgcn_mfma_f32_16x16x32_bf16(pah, vh, oacc[fn], 0, 0, 0);
                oacc[fn] = __builtin_amdgcn_mfma_f32_16x16x32_bf16(pal, vh, oacc[fn], 0, 0, 0);
                oacc[fn] = __builtin_amdgcn_mfma_f32_16x16x32_bf16(pah, vl, oacc[fn], 0, 0, 0);
            }
        }
    }

    // ---- epilogue: ctx[row][h*80 + d] = O/l (fp32 or bf16 hi/lo planes)
#pragma unroll
    for (int q = 0; q < 4; ++q) {
        float inv = 1.f / lrun[q];
        size_t rowoff = (size_t)(r0 + wrow + lg * 4 + q) * EMBED + h * HD;
        if (PLANES) {
#pragma unroll
            for (int fn = 0; fn < 5; ++fn) {
                float val = oacc[fn][q] * inv;
                unsigned short hb = f2bf(val);
                ctxh[rowoff + fn * 16 + col] = hb;
                ctxl[rowoff + fn * 16 + col] = f2bf(val - bf2f(hb));
            }
        } else {
#pragma unroll
            for (int fn = 0; fn < 5; ++fn)
                ctx[rowoff + fn * 16 + col] = oacc[fn][q] * inv;
        }
    }
}

// ---------------------------------------------------------------------------
extern "C" void kernel_launch(void* const* d_in, const int* in_sizes, int n_in,
                              void* d_out, int out_size, void* d_ws, size_t ws_size,
                              hipStream_t stream)
{
    const float* x      = (const float*)d_in[0];
    const float* rpe    = (const float*)d_in[1];
    const int*   cu     = (const int*)d_in[2];
    // d_in[3] = max_seqlen (unused)
    const float* qkv_w  = (const float*)d_in[4];
    const float* qkv_b  = (const float*)d_in[5];
    const float* proj_w = (const float*)d_in[6];
    const float* proj_b = (const float*)d_in[7];

    float* ws  = (float*)d_ws;
    float* Q   = ws;                                 // R0: fp32 2.62M
    float* K   = ws + (size_t)QKV_STRIDE;            // R1
    float* V   = ws + (size_t)2 * QKV_STRIDE;        // R2
    float* ctx = ws + (size_t)3 * QKV_STRIDE;        // R3 (10.5MB)

    const int nseg = in_sizes[2] - 1;

    // Hoisted path needs R3 (x planes) + R4 (w planes, later ctx planes)
    // + R5 (proj_w planes): 68,157,440 bytes total. (Proven present.)
    const bool HOIST = ws_size >= 68157440ULL;

    if (HOIST) {
        unsigned short* xh   = (unsigned short*)(ws + (size_t)3 * QKV_STRIDE);    // R3
        unsigned short* xl   = xh + (size_t)SEQL * EMBED;
        unsigned short* wh   = (unsigned short*)(ws + (size_t)4 * QKV_STRIDE);    // R4
        unsigned short* wl   = wh + (size_t)QKV_N * EMBED;
        unsigned short* ctxh = (unsigned short*)(ws + (size_t)4 * QKV_STRIDE);    // overlays wh/wl
        unsigned short* ctxl = ctxh + (size_t)SEQL * EMBED;
        unsigned short* ph   = (unsigned short*)((char*)d_ws + 61603840);         // R5
        unsigned short* pl   = ph + (size_t)EMBED * EMBED;

        const int c0 = SEQL * EMBED / 4, c1 = QKV_N * EMBED / 4, c2 = EMBED * EMBED / 4;

        // 0) pre-split all three operands (one launch)
        split3_kernel<<<(c0 + c1 + c2 + 255) / 256, 256, 0, stream>>>(
            x, xh, xl, c0, qkv_w, wh, wl, c1, proj_w, ph, pl, c2);

        // 1) QKV projection (dbuf gload_lds pipeline) -> Q/K/V [head][seq][dim]
        gemm_mfma_pre_kernel<1><<<dim3(QKV_N / 128, SEQL / 128), 256, 0, stream>>>(
            xh, xl, wh, wl, qkv_b, Q, SEQL, QKV_N, EMBED);

        // 2) rotary on Q,K in place
        rotary_kernel<<<(2 * NHEAD * SEQL * ROT) / 256, 256, 0, stream>>>(Q, K, rpe);

        // 3) attention -> ctx planes directly (w planes dead by now)
        attn_mfma_kernel<1><<<dim3(SEQL / 64, NHEAD), 256, 0, stream>>>(
            Q, K, V, cu, nseg, nullptr, ctxh, ctxl);

        // 4) output projection (dbuf gload_lds pipeline)
        gemm_mfma_pre_kernel<0><<<dim3(EMBED / 128, SEQL / 128), 256, 0, stream>>>(
            ctxh, ctxl, ph, pl, proj_b, (float*)d_out, SEQL, EMBED, EMBED);
    } else {
        // fallback: fully-validated round-3 pipeline with round-4 attention
        gemm_mfma_kernel<1><<<dim3(QKV_N / 128, SEQL / 128), 256, 0, stream>>>(
            x, qkv_w, qkv_b, Q, SEQL, QKV_N, EMBED);
        rotary_kernel<<<(2 * NHEAD * SEQL * ROT) / 256, 256, 0, stream>>>(Q, K, rpe);
        attn_mfma_kernel<0><<<dim3(SEQL / 64, NHEAD), 256, 0, stream>>>(
            Q, K, V, cu, nseg, ctx, nullptr, nullptr);
        gemm_mfma_kernel<0><<<dim3(EMBED / 128, SEQL / 128), 256, 0, stream>>>(
            ctx, proj_w, proj_b, (float*)d_out, SEQL, EMBED, EMBED);
    }
}

// Round 13
// 259.204 us; speedup vs baseline: 1.1532x; 1.0628x over previous
//
#include <hip/hip_runtime.h>
#include <hip/hip_bf16.h>
#include <cstdint>
#include <cstddef>

#define EMBED 1280
#define NHEAD 16
#define HD 80
#define ROT 40
#define SEQL 2048
#define QKV_N 3840
#define QKV_STRIDE (NHEAD * SEQL * HD)   // elems per Q/K/V buffer = 2,621,440

typedef __attribute__((ext_vector_type(8))) short short8v;  // 8 bf16 (4 VGPRs)
typedef __attribute__((ext_vector_type(4))) short short4v;  // 4 bf16 (8B)
typedef __attribute__((ext_vector_type(4))) float f32x4;    // MFMA accumulator

__device__ inline unsigned short f2bf(float f) {            // RNE float->bf16
    unsigned u = __float_as_uint(f);
    u += 0x7FFFu + ((u >> 16) & 1u);
    return (unsigned short)(u >> 16);
}
__device__ inline float bf2f(unsigned short h) {
    return __uint_as_float(((unsigned)h) << 16);
}

// 16B async global->LDS (linear dest = wave base + lane*16; size literal 16)
#define GLD16(GP, LP)                                                         \
    __builtin_amdgcn_global_load_lds(                                         \
        (const __attribute__((address_space(1))) unsigned int*)(GP),          \
        (__attribute__((address_space(3))) unsigned int*)(LP), 16, 0, 0)

// ---------------------------------------------------------------------------
// Fused fp32 -> bf16 hi/lo split for the 3 GEMM operands (1 launch)
// ---------------------------------------------------------------------------
__global__ __launch_bounds__(256) void split3_kernel(
    const float* __restrict__ s0, unsigned short* __restrict__ h0, unsigned short* __restrict__ l0, int c0,
    const float* __restrict__ s1, unsigned short* __restrict__ h1, unsigned short* __restrict__ l1, int c1,
    const float* __restrict__ s2, unsigned short* __restrict__ h2, unsigned short* __restrict__ l2, int c2)
{
    int i = blockIdx.x * 256 + threadIdx.x;
    const float* s; unsigned short *hp, *lp; int base;
    if (i < c0)               { s = s0; hp = h0; lp = l0; base = i; }
    else if (i < c0 + c1)     { s = s1; hp = h1; lp = l1; base = i - c0; }
    else if (i < c0 + c1 + c2){ s = s2; hp = h2; lp = l2; base = i - c0 - c1; }
    else return;
    float4 v = reinterpret_cast<const float4*>(s)[base];
    unsigned short a0 = f2bf(v.x), a1 = f2bf(v.y), a2 = f2bf(v.z), a3 = f2bf(v.w);
    short4v hv, lv;
    hv[0] = (short)a0; hv[1] = (short)a1; hv[2] = (short)a2; hv[3] = (short)a3;
    lv[0] = (short)f2bf(v.x - bf2f(a0));
    lv[1] = (short)f2bf(v.y - bf2f(a1));
    lv[2] = (short)f2bf(v.z - bf2f(a2));
    lv[3] = (short)f2bf(v.w - bf2f(a3));
    *reinterpret_cast<short4v*>(&hp[base * 4]) = hv;
    *reinterpret_cast<short4v*>(&lp[base * 4]) = lv;
}

// ---------------------------------------------------------------------------
// bf16x3 split MFMA GEMM, FALLBACK variant (validated round 3; in-loop conv)
// ---------------------------------------------------------------------------
template <int MODE>
__global__ __launch_bounds__(256) void gemm_mfma_kernel(
    const float* __restrict__ A, const float* __restrict__ B,
    const float* __restrict__ bias, float* __restrict__ C,
    int M, int N, int K)
{
    __shared__ unsigned short As[2 * 128 * 32];   // 16 KB
    __shared__ unsigned short Bs[2 * 128 * 32];   // 16 KB

    const int tid  = threadIdx.x;
    const int m0   = blockIdx.y * 128;
    const int n0   = blockIdx.x * 128;
    const int wave = tid >> 6;
    const int lane = tid & 63;
    const int wm   = (wave >> 1) * 64;
    const int wn   = (wave & 1) * 64;
    const int lrow = lane & 15;
    const int lg   = lane >> 4;          // k-group 0..3

    f32x4 acc[4][4];
#pragma unroll
    for (int i = 0; i < 4; ++i)
#pragma unroll
        for (int j = 0; j < 4; ++j) acc[i][j] = (f32x4){0.f, 0.f, 0.f, 0.f};

    for (int k0 = 0; k0 < K; k0 += 32) {
        float4 ar[4], br[4];
#pragma unroll
        for (int l = 0; l < 4; ++l) {
            int id = l * 256 + tid;          // 0..1023 = 128 rows x 8 float4
            int r = id >> 3, c = id & 7;
            ar[l] = *reinterpret_cast<const float4*>(&A[(size_t)(m0 + r) * K + k0 + c * 4]);
            br[l] = *reinterpret_cast<const float4*>(&B[(size_t)(n0 + r) * K + k0 + c * 4]);
        }
        __syncthreads();
#pragma unroll
        for (int l = 0; l < 4; ++l) {
            int id = l * 256 + tid;
            int r = id >> 3, c = id & 7;
            int base = r * 32 + (((c >> 1) ^ (r & 3)) << 3) + ((c & 1) << 2);
            float4 v = ar[l];
            unsigned short h0 = f2bf(v.x), h1 = f2bf(v.y), h2 = f2bf(v.z), h3 = f2bf(v.w);
            unsigned short g0 = f2bf(v.x - bf2f(h0)), g1 = f2bf(v.y - bf2f(h1));
            unsigned short g2 = f2bf(v.z - bf2f(h2)), g3 = f2bf(v.w - bf2f(h3));
            uint2 w;
            w.x = (unsigned)h0 | ((unsigned)h1 << 16); w.y = (unsigned)h2 | ((unsigned)h3 << 16);
            *reinterpret_cast<uint2*>(&As[base]) = w;
            w.x = (unsigned)g0 | ((unsigned)g1 << 16); w.y = (unsigned)g2 | ((unsigned)g3 << 16);
            *reinterpret_cast<uint2*>(&As[4096 + base]) = w;
            v = br[l];
            h0 = f2bf(v.x); h1 = f2bf(v.y); h2 = f2bf(v.z); h3 = f2bf(v.w);
            g0 = f2bf(v.x - bf2f(h0)); g1 = f2bf(v.y - bf2f(h1));
            g2 = f2bf(v.z - bf2f(h2)); g3 = f2bf(v.w - bf2f(h3));
            w.x = (unsigned)h0 | ((unsigned)h1 << 16); w.y = (unsigned)h2 | ((unsigned)h3 << 16);
            *reinterpret_cast<uint2*>(&Bs[base]) = w;
            w.x = (unsigned)g0 | ((unsigned)g1 << 16); w.y = (unsigned)g2 | ((unsigned)g3 << 16);
            *reinterpret_cast<uint2*>(&Bs[4096 + base]) = w;
        }
        __syncthreads();
        short8v bh[4], bl[4];
#pragma unroll
        for (int fn = 0; fn < 4; ++fn) {
            int row = wn + fn * 16 + lrow;
            int idx = row * 32 + ((lg ^ (row & 3)) << 3);
            bh[fn] = *reinterpret_cast<const short8v*>(&Bs[idx]);
            bl[fn] = *reinterpret_cast<const short8v*>(&Bs[4096 + idx]);
        }
#pragma unroll
        for (int fm = 0; fm < 4; ++fm) {
            int row = wm + fm * 16 + lrow;
            int idx = row * 32 + ((lg ^ (row & 3)) << 3);
            short8v ah = *reinterpret_cast<const short8v*>(&As[idx]);
            short8v al = *reinterpret_cast<const short8v*>(&As[4096 + idx]);
#pragma unroll
            for (int fn = 0; fn < 4; ++fn) {
                acc[fm][fn] = __builtin_amdgcn_mfma_f32_16x16x32_bf16(ah, bh[fn], acc[fm][fn], 0, 0, 0);
                acc[fm][fn] = __builtin_amdgcn_mfma_f32_16x16x32_bf16(ah, bl[fn], acc[fm][fn], 0, 0, 0);
                acc[fm][fn] = __builtin_amdgcn_mfma_f32_16x16x32_bf16(al, bh[fn], acc[fm][fn], 0, 0, 0);
            }
        }
    }

#pragma unroll
    for (int fn = 0; fn < 4; ++fn) {
        int n = n0 + wn + fn * 16 + lrow;
        float bcol = bias[n];
        if (MODE == 0) {
#pragma unroll
            for (int fm = 0; fm < 4; ++fm) {
#pragma unroll
                for (int q = 0; q < 4; ++q) {
                    int m = m0 + wm + fm * 16 + lg * 4 + q;
                    C[(size_t)m * N + n] = acc[fm][fn][q] + bcol;
                }
            }
        } else {
            int part = n / EMBED;
            int rem  = n - part * EMBED;
            int head = rem / HD;
            int d    = rem - head * HD;
            float* dst = C + (size_t)part * QKV_STRIDE + (size_t)head * SEQL * HD + d;
#pragma unroll
            for (int fm = 0; fm < 4; ++fm) {
#pragma unroll
                for (int q = 0; q < 4; ++q) {
                    int m = m0 + wm + fm * 16 + lg * 4 + q;
                    dst[(size_t)m * HD] = acc[fm][fn][q] + bcol;
                }
            }
        }
    }
}

// ---------------------------------------------------------------------------
// bf16x3 split MFMA GEMM, HOISTED variant (round-11 structure: dbuf +
// global_load_lds issue-early; at the 128^2-structure ceiling ~875 TF).
// MODE 0: C row-major fp32.  MODE 1: Q,K -> fp32 scatter [head][seq][dim];
// V -> V^T bf16 hi/lo planes [head][d][seq] (vth/vtl).
// ---------------------------------------------------------------------------
template <int MODE>
__global__ __launch_bounds__(256) void gemm_mfma_pre_kernel(
    const unsigned short* __restrict__ Ah, const unsigned short* __restrict__ Al,
    const unsigned short* __restrict__ Bh, const unsigned short* __restrict__ Bl,
    const float* __restrict__ bias, float* __restrict__ C,
    unsigned short* __restrict__ vth, unsigned short* __restrict__ vtl,
    int M, int N, int K)
{
    __shared__ unsigned short As[2][2 * 128 * 32];   // 2 bufs x (hi|lo) 16 KB
    __shared__ unsigned short Bs[2][2 * 128 * 32];   // total 64 KB

    const int tid  = threadIdx.x;
    const int m0   = blockIdx.y * 128;
    const int n0   = blockIdx.x * 128;
    const int wave = tid >> 6;
    const int lane = tid & 63;
    const int wm   = (wave >> 1) * 64;
    const int wn   = (wave & 1) * 64;
    const int lrow = lane & 15;
    const int lg   = lane >> 4;          // k-group 0..3

    f32x4 acc[4][4];
#pragma unroll
    for (int i = 0; i < 4; ++i)
#pragma unroll
        for (int j = 0; j < 4; ++j) acc[i][j] = (f32x4){0.f, 0.f, 0.f, 0.f};

    const int r0s = tid >> 2;
    const int r1s = (256 + tid) >> 2;
    const int b0  = tid & 3;
    const int bs0 = b0 ^ (r0s & 3);
    const int bs1 = b0 ^ (r1s & 3);
    const size_t ga0 = (size_t)(m0 + r0s) * K + bs0 * 8;
    const size_t ga1 = (size_t)(m0 + r1s) * K + bs1 * 8;
    const size_t gb0 = (size_t)(n0 + r0s) * K + bs0 * 8;
    const size_t gb1 = (size_t)(n0 + r1s) * K + bs1 * 8;
    const int lo0 = (tid & ~63) * 8;            // wave-uniform LDS offsets
    const int lo1 = (256 + (tid & ~63)) * 8;

    // prologue: stage tile 0 into buffer 0
    GLD16(Ah + ga0, &As[0][lo0]);
    GLD16(Ah + ga1, &As[0][lo1]);
    GLD16(Al + ga0, &As[0][lo0 + 4096]);
    GLD16(Al + ga1, &As[0][lo1 + 4096]);
    GLD16(Bh + gb0, &Bs[0][lo0]);
    GLD16(Bh + gb1, &Bs[0][lo1]);
    GLD16(Bl + gb0, &Bs[0][lo0 + 4096]);
    GLD16(Bl + gb1, &Bs[0][lo1 + 4096]);
    __syncthreads();

    const int NT = K >> 5;               // 40 for both GEMMs
    for (int t = 0; t < NT; ++t) {
        const int cur = t & 1, nxt = cur ^ 1;
        if (t + 1 < NT) {
            const size_t k1 = (size_t)(t + 1) * 32;
            GLD16(Ah + ga0 + k1, &As[nxt][lo0]);
            GLD16(Ah + ga1 + k1, &As[nxt][lo1]);
            GLD16(Al + ga0 + k1, &As[nxt][lo0 + 4096]);
            GLD16(Al + ga1 + k1, &As[nxt][lo1 + 4096]);
            GLD16(Bh + gb0 + k1, &Bs[nxt][lo0]);
            GLD16(Bh + gb1 + k1, &Bs[nxt][lo1]);
            GLD16(Bl + gb0 + k1, &Bs[nxt][lo0 + 4096]);
            GLD16(Bl + gb1 + k1, &Bs[nxt][lo1 + 4096]);
        }
        short8v bh[4], bl[4];
#pragma unroll
        for (int fn = 0; fn < 4; ++fn) {
            int row = wn + fn * 16 + lrow;
            int idx = row * 32 + ((lg ^ (row & 3)) << 3);
            bh[fn] = *reinterpret_cast<const short8v*>(&Bs[cur][idx]);
            bl[fn] = *reinterpret_cast<const short8v*>(&Bs[cur][4096 + idx]);
        }
#pragma unroll
        for (int fm = 0; fm < 4; ++fm) {
            int row = wm + fm * 16 + lrow;
            int idx = row * 32 + ((lg ^ (row & 3)) << 3);
            short8v ah = *reinterpret_cast<const short8v*>(&As[cur][idx]);
            short8v al = *reinterpret_cast<const short8v*>(&As[cur][4096 + idx]);
#pragma unroll
            for (int fn = 0; fn < 4; ++fn) {
                acc[fm][fn] = __builtin_amdgcn_mfma_f32_16x16x32_bf16(ah, bh[fn], acc[fm][fn], 0, 0, 0);
                acc[fm][fn] = __builtin_amdgcn_mfma_f32_16x16x32_bf16(ah, bl[fn], acc[fm][fn], 0, 0, 0);
                acc[fm][fn] = __builtin_amdgcn_mfma_f32_16x16x32_bf16(al, bh[fn], acc[fm][fn], 0, 0, 0);
            }
        }
        __syncthreads();
    }

#pragma unroll
    for (int fn = 0; fn < 4; ++fn) {
        int n = n0 + wn + fn * 16 + lrow;
        float bcol = bias[n];
        if (MODE == 0) {
#pragma unroll
            for (int fm = 0; fm < 4; ++fm) {
#pragma unroll
                for (int q = 0; q < 4; ++q) {
                    int m = m0 + wm + fm * 16 + lg * 4 + q;
                    C[(size_t)m * N + n] = acc[fm][fn][q] + bcol;
                }
            }
        } else {
            int part = n / EMBED;
            int rem  = n - part * EMBED;
            int head = rem / HD;
            int d    = rem - head * HD;
            if (part < 2) {           // Q, K -> fp32 (rotary consumes these)
                float* dst = C + (size_t)part * QKV_STRIDE + (size_t)head * SEQL * HD + d;
#pragma unroll
                for (int fm = 0; fm < 4; ++fm) {
#pragma unroll
                    for (int q = 0; q < 4; ++q) {
                        int m = m0 + wm + fm * 16 + lg * 4 + q;
                        dst[(size_t)m * HD] = acc[fm][fn][q] + bcol;
                    }
                }
            } else {                  // V -> V^T bf16 hi/lo planes [h][d][seq]
                size_t base = ((size_t)head * HD + d) * SEQL;
#pragma unroll
                for (int fm = 0; fm < 4; ++fm) {
#pragma unroll
                    for (int q = 0; q < 4; ++q) {
                        int m = m0 + wm + fm * 16 + lg * 4 + q;
                        float val = acc[fm][fn][q] + bcol;
                        unsigned short hb = f2bf(val);
                        vth[base + m] = hb;
                        vtl[base + m] = f2bf(val - bf2f(hb));
                    }
                }
            }
        }
    }
}

// ---------------------------------------------------------------------------
// Rotary OLD (in-place fp32) — fallback path only
// ---------------------------------------------------------------------------
__global__ __launch_bounds__(256) void rotary_kernel(
    float* __restrict__ Q, float* __restrict__ K, const float* __restrict__ rpe)
{
    int idx = blockIdx.x * 256 + threadIdx.x;
    int r = idx % ROT;
    int s = (idx / ROT) & (SEQL - 1);
    int h = (idx / (ROT * SEQL)) & (NHEAD - 1);
    float* buf = (idx >= NHEAD * SEQL * ROT) ? K : Q;
    float* p = buf + ((size_t)h * SEQL + s) * HD;
    float ang = rpe[s * ROT + r];
    float c = cosf(ang), sn = sinf(ang);
    float t1 = p[r], t2 = p[r + ROT];
    p[r]       = t1 * c - t2 * sn;
    p[r + ROT] = t2 * c + t1 * sn;
}

// ---------------------------------------------------------------------------
// Rotary NEW: read fp32 Q/K, rotate, fold 1/sqrt(HD) into Q, emit bf16 hi/lo
// planes [h][seq][80]. Same f2bf on same fp32 values the attn kernel used to
// compute internally -> bit-identical numerics.
// ---------------------------------------------------------------------------
__global__ __launch_bounds__(256) void rotary_split_kernel(
    const float* __restrict__ Qf, const float* __restrict__ Kf,
    const float* __restrict__ rpe,
    unsigned short* __restrict__ qh, unsigned short* __restrict__ ql,
    unsigned short* __restrict__ kh, unsigned short* __restrict__ kl)
{
    int idx = blockIdx.x * 256 + threadIdx.x;   // 0 .. 2*16*2048*40-1
    int r = idx % ROT;
    int s = (idx / ROT) & (SEQL - 1);
    int h = (idx / (ROT * SEQL)) & (NHEAD - 1);
    bool isK = idx >= NHEAD * SEQL * ROT;
    const float* src = isK ? Kf : Qf;
    unsigned short* oh = isK ? kh : qh;
    unsigned short* ol = isK ? kl : ql;
    const float sc = isK ? 1.f : 0.11180339887498949f;   // 1/sqrt(80) into Q
    const float* p = src + ((size_t)h * SEQL + s) * HD;
    float ang = rpe[s * ROT + r];
    float c = cosf(ang), sn = sinf(ang);
    float t1 = p[r], t2 = p[r + ROT];
    float a = (t1 * c - t2 * sn) * sc;
    float b = (t2 * c + t1 * sn) * sc;
    size_t o = ((size_t)h * SEQL + s) * HD;
    unsigned short ha = f2bf(a);
    oh[o + r] = ha;       ol[o + r] = f2bf(a - bf2f(ha));
    unsigned short hb = f2bf(b);
    oh[o + r + ROT] = hb; ol[o + r + ROT] = f2bf(b - bf2f(hb));
}

#define KSTR 104
#define VSTR 72
#define PSTR 72

// ---------------------------------------------------------------------------
// MFMA flash attention OLD (fp32 inputs, in-kernel conversion) — fallback.
// ---------------------------------------------------------------------------
template <int PLANES>
__global__ __launch_bounds__(256) void attn_mfma_kernel(
    const float* __restrict__ Qb, const float* __restrict__ Kb,
    const float* __restrict__ Vb, const int* __restrict__ cu, int nseg,
    float* __restrict__ ctx, unsigned short* __restrict__ ctxh,
    unsigned short* __restrict__ ctxl)
{
    __shared__ unsigned short kv_hi[64 * KSTR];
    __shared__ unsigned short kv_lo[64 * KSTR];
    __shared__ unsigned short p_hi[64 * PSTR];
    __shared__ unsigned short p_lo[64 * PSTR];

    const int tid  = threadIdx.x;
    const int lane = tid & 63;
    const int wave = tid >> 6;
    const int lg   = lane >> 4;
    const int col  = lane & 15;
    const int h    = blockIdx.y;
    const int r0   = blockIdx.x * 64;
    const int wrow = wave * 16;

    int qstart[4], qend[4];
#pragma unroll
    for (int q = 0; q < 4; ++q) {
        int row = r0 + wrow + lg * 4 + q;
        int sid = 0;
        for (int i = 1; i <= nseg; ++i) sid += (cu[i] <= row);
        qstart[q] = (sid == 0) ? 0 : cu[sid];
        qend[q]   = (sid >= nseg) ? SEQL : cu[sid + 1];
    }
    int blo, bhi;
    {
        int sid = 0;
        for (int i = 1; i <= nseg; ++i) sid += (cu[i] <= r0);
        blo = (sid == 0) ? 0 : cu[sid];
        sid = 0;
        for (int i = 1; i <= nseg; ++i) sid += (cu[i] <= r0 + 63);
        bhi = (sid >= nseg) ? SEQL : cu[sid + 1];
    }

    const float scale = 0.11180339887498949f;
    short8v qhf[3], qlf[3];
    {
        const float* Qr = Qb + ((size_t)h * SEQL + r0 + wrow + col) * HD;
#pragma unroll
        for (int kc = 0; kc < 3; ++kc) {
            int d0 = kc * 32 + lg * 8;
            float v[8];
            if (d0 < HD) {
                float4 f0 = *reinterpret_cast<const float4*>(&Qr[d0]);
                float4 f1 = *reinterpret_cast<const float4*>(&Qr[d0 + 4]);
                v[0] = f0.x * scale; v[1] = f0.y * scale; v[2] = f0.z * scale; v[3] = f0.w * scale;
                v[4] = f1.x * scale; v[5] = f1.y * scale; v[6] = f1.z * scale; v[7] = f1.w * scale;
            } else {
#pragma unroll
                for (int j = 0; j < 8; ++j) v[j] = 0.f;
            }
            short8v hh, ll;
#pragma unroll
            for (int j = 0; j < 8; ++j) {
                unsigned short hb = f2bf(v[j]);
                hh[j] = (short)hb;
                ll[j] = (short)f2bf(v[j] - bf2f(hb));
            }
            qhf[kc] = hh; qlf[kc] = ll;
        }
    }

    f32x4 oacc[5];
#pragma unroll
    for (int fn = 0; fn < 5; ++fn) oacc[fn] = (f32x4){0.f, 0.f, 0.f, 0.f};
    float mrun[4] = {-1e30f, -1e30f, -1e30f, -1e30f};
    float lrun[4] = {0.f, 0.f, 0.f, 0.f};

    const float* Kh = Kb + (size_t)h * SEQL * HD;
    const float* Vh = Vb + (size_t)h * SEQL * HD;

    for (int kb = (blo & ~63); kb < bhi; kb += 64) {
        __syncthreads();
        const float* Kt = Kh + (size_t)kb * HD;
#pragma unroll
        for (int l = 0; l < 5; ++l) {
            int idx = tid + l * 256;
            int ky = idx / 20, fc = idx % 20;
            float4 f = *reinterpret_cast<const float4*>(&Kt[ky * HD + fc * 4]);
            int base = ky * KSTR + fc * 4;
            unsigned short h0 = f2bf(f.x), h1 = f2bf(f.y), h2 = f2bf(f.z), h3 = f2bf(f.w);
            uint2 w;
            w.x = (unsigned)h0 | ((unsigned)h1 << 16); w.y = (unsigned)h2 | ((unsigned)h3 << 16);
            *reinterpret_cast<uint2*>(&kv_hi[base]) = w;
            h0 = f2bf(f.x - bf2f(h0)); h1 = f2bf(f.y - bf2f(h1));
            h2 = f2bf(f.z - bf2f(h2)); h3 = f2bf(f.w - bf2f(h3));
            w.x = (unsigned)h0 | ((unsigned)h1 << 16); w.y = (unsigned)h2 | ((unsigned)h3 << 16);
            *reinterpret_cast<uint2*>(&kv_lo[base]) = w;
        }
        {
            int ky = tid >> 2, off = (tid & 3) << 2;
            uint2 z; z.x = 0u; z.y = 0u;
            *reinterpret_cast<uint2*>(&kv_hi[ky * KSTR + 80 + off]) = z;
            *reinterpret_cast<uint2*>(&kv_lo[ky * KSTR + 80 + off]) = z;
        }
        __syncthreads();

        f32x4 sfr[4];
#pragma unroll
        for (int kt = 0; kt < 4; ++kt) {
            f32x4 s = (f32x4){0.f, 0.f, 0.f, 0.f};
#pragma unroll
            for (int kc = 0; kc < 3; ++kc) {
                int bidx = (kt * 16 + col) * KSTR + kc * 32 + lg * 8;
                short8v khf = *reinterpret_cast<const short8v*>(&kv_hi[bidx]);
                short8v klf = *reinterpret_cast<const short8v*>(&kv_lo[bidx]);
                s = __builtin_amdgcn_mfma_f32_16x16x32_bf16(qhf[kc], khf, s, 0, 0, 0);
                s = __builtin_amdgcn_mfma_f32_16x16x32_bf16(qlf[kc], khf, s, 0, 0, 0);
                s = __builtin_amdgcn_mfma_f32_16x16x32_bf16(qhf[kc], klf, s, 0, 0, 0);
            }
            sfr[kt] = s;
        }
        __syncthreads();

        const float* Vt = Vh + (size_t)kb * HD;
        float4 vreg[5];
#pragma unroll
        for (int l = 0; l < 5; ++l) {
            int idx = tid + l * 256;
            int fc = idx >> 6, ky = idx & 63;
            vreg[l] = *reinterpret_cast<const float4*>(&Vt[ky * HD + fc * 4]);
        }

#pragma unroll
        for (int q = 0; q < 4; ++q) {
            float sv[4];
            float mx = -1e30f;
#pragma unroll
            for (int kt = 0; kt < 4; ++kt) {
                int key = kb + kt * 16 + col;
                bool ok = (key >= qstart[q]) && (key < qend[q]);
                sv[kt] = ok ? sfr[kt][q] : -1e30f;
                mx = fmaxf(mx, sv[kt]);
            }
            mx = fmaxf(mx, __shfl_xor(mx, 1));
            mx = fmaxf(mx, __shfl_xor(mx, 2));
            mx = fmaxf(mx, __shfl_xor(mx, 4));
            mx = fmaxf(mx, __shfl_xor(mx, 8));
            float mnew  = fmaxf(mrun[q], mx);
            float alpha = __expf(mrun[q] - mnew);
            float ps = 0.f;
            int prow = (wrow + lg * 4 + q) * PSTR;
#pragma unroll
            for (int kt = 0; kt < 4; ++kt) {
                float p = (sv[kt] > -1e29f) ? __expf(sv[kt] - mnew) : 0.f;
                ps += p;
                unsigned short ph = f2bf(p);
                p_hi[prow + kt * 16 + col] = ph;
                p_lo[prow + kt * 16 + col] = f2bf(p - bf2f(ph));
            }
            ps += __shfl_xor(ps, 1);
            ps += __shfl_xor(ps, 2);
            ps += __shfl_xor(ps, 4);
            ps += __shfl_xor(ps, 8);
            lrun[q] = lrun[q] * alpha + ps;
            mrun[q] = mnew;
#pragma unroll
            for (int fn = 0; fn < 5; ++fn) oacc[fn][q] *= alpha;
        }

#pragma unroll
        for (int l = 0; l < 5; ++l) {
            int idx = tid + l * 256;
            int fc = idx >> 6, ky = idx & 63;
            float4 f = vreg[l];
            float vv[4] = {f.x, f.y, f.z, f.w};
#pragma unroll
            for (int e = 0; e < 4; ++e) {
                unsigned short hb = f2bf(vv[e]);
                kv_hi[(fc * 4 + e) * VSTR + ky] = hb;
                kv_lo[(fc * 4 + e) * VSTR + ky] = f2bf(vv[e] - bf2f(hb));
            }
        }
        __syncthreads();

#pragma unroll
        for (int kc2 = 0; kc2 < 2; ++kc2) {
            int aidx = (wrow + col) * PSTR + kc2 * 32 + lg * 8;
            short8v pah = *reinterpret_cast<const short8v*>(&p_hi[aidx]);
            short8v pal = *reinterpret_cast<const short8v*>(&p_lo[aidx]);
#pragma unroll
            for (int fn = 0; fn < 5; ++fn) {
                int bidx = (fn * 16 + col) * VSTR + kc2 * 32 + lg * 8;
                short8v vh = *reinterpret_cast<const short8v*>(&kv_hi[bidx]);
                short8v vl = *reinterpret_cast<const short8v*>(&kv_lo[bidx]);
                oacc[fn] = __builtin_amdgcn_mfma_f32_16x16x32_bf16(pah, vh, oacc[fn], 0, 0, 0);
                oacc[fn] = __builtin_amdgcn_mfma_f32_16x16x32_bf16(pal, vh, oacc[fn], 0, 0, 0);
                oacc[fn] = __builtin_amdgcn_mfma_f32_16x16x32_bf16(pah, vl, oacc[fn], 0, 0, 0);
            }
        }
    }

#pragma unroll
    for (int q = 0; q < 4; ++q) {
        float inv = 1.f / lrun[q];
        size_t rowoff = (size_t)(r0 + wrow + lg * 4 + q) * EMBED + h * HD;
        if (PLANES) {
#pragma unroll
            for (int fn = 0; fn < 5; ++fn) {
                float val = oacc[fn][q] * inv;
                unsigned short hb = f2bf(val);
                ctxh[rowoff + fn * 16 + col] = hb;
                ctxl[rowoff + fn * 16 + col] = f2bf(val - bf2f(hb));
            }
        } else {
#pragma unroll
            for (int fn = 0; fn < 5; ++fn)
                ctx[rowoff + fn * 16 + col] = oacc[fn][q] * inv;
        }
    }
}

// ---------------------------------------------------------------------------
// MFMA flash attention NEW: all inputs pre-split bf16 hi/lo planes.
// Q/K planes [h][seq][80] (Q pre-scaled); V^T planes [h][d][seq].
// Staging = pure 8B copies (no conversion VALU, no transpose scatter).
// MFMA / softmax / barriers byte-identical to the validated kernel.
// ---------------------------------------------------------------------------
__global__ __launch_bounds__(256) void attn_mfma2_kernel(
    const unsigned short* __restrict__ qh, const unsigned short* __restrict__ ql,
    const unsigned short* __restrict__ kh, const unsigned short* __restrict__ kl,
    const unsigned short* __restrict__ vth, const unsigned short* __restrict__ vtl,
    const int* __restrict__ cu, int nseg,
    unsigned short* __restrict__ ctxh, unsigned short* __restrict__ ctxl)
{
    __shared__ unsigned short kv_hi[64 * KSTR];   // K: [key][104] | V: [d][72]
    __shared__ unsigned short kv_lo[64 * KSTR];
    __shared__ unsigned short p_hi[64 * PSTR];
    __shared__ unsigned short p_lo[64 * PSTR];

    const int tid  = threadIdx.x;
    const int lane = tid & 63;
    const int wave = tid >> 6;
    const int lg   = lane >> 4;        // 0..3
    const int col  = lane & 15;
    const int h    = blockIdx.y;
    const int r0   = blockIdx.x * 64;
    const int wrow = wave * 16;

    // --- segment bounds: exact searchsorted(cu[1:], pos, 'right') semantics
    int qstart[4], qend[4];
#pragma unroll
    for (int q = 0; q < 4; ++q) {
        int row = r0 + wrow + lg * 4 + q;
        int sid = 0;
        for (int i = 1; i <= nseg; ++i) sid += (cu[i] <= row);
        qstart[q] = (sid == 0) ? 0 : cu[sid];
        qend[q]   = (sid >= nseg) ? SEQL : cu[sid + 1];
    }
    int blo, bhi;
    {
        int sid = 0;
        for (int i = 1; i <= nseg; ++i) sid += (cu[i] <= r0);
        blo = (sid == 0) ? 0 : cu[sid];
        sid = 0;
        for (int i = 1; i <= nseg; ++i) sid += (cu[i] <= r0 + 63);
        bhi = (sid >= nseg) ? SEQL : cu[sid + 1];
    }

    // --- Q fragments straight from planes (pre-scaled, pre-rotated)
    short8v qfh[3], qfl[3];
    {
        const unsigned short* Qh_ = qh + ((size_t)h * SEQL + r0 + wrow + col) * HD;
        const unsigned short* Ql_ = ql + ((size_t)h * SEQL + r0 + wrow + col) * HD;
#pragma unroll
        for (int kc = 0; kc < 3; ++kc) {
            int d0 = kc * 32 + lg * 8;
            if (d0 < HD) {
                qfh[kc] = *reinterpret_cast<const short8v*>(&Qh_[d0]);
                qfl[kc] = *reinterpret_cast<const short8v*>(&Ql_[d0]);
            } else {
                short8v z = {0,0,0,0,0,0,0,0};
                qfh[kc] = z; qfl[kc] = z;
            }
        }
    }

    f32x4 oacc[5];
#pragma unroll
    for (int fn = 0; fn < 5; ++fn) oacc[fn] = (f32x4){0.f, 0.f, 0.f, 0.f};
    float mrun[4] = {-1e30f, -1e30f, -1e30f, -1e30f};
    float lrun[4] = {0.f, 0.f, 0.f, 0.f};

    const unsigned short* Khp = kh + (size_t)h * SEQL * HD;
    const unsigned short* Klp = kl + (size_t)h * SEQL * HD;
    const unsigned short* Vhp = vth + (size_t)h * HD * SEQL;
    const unsigned short* Vlp = vtl + (size_t)h * HD * SEQL;

    for (int kb = (blo & ~63); kb < bhi; kb += 64) {
        __syncthreads();                 // prior PV reads of kv/pbuf done

        // ---- stage K tile: pure 8B copies from planes -> [key][104]
        const unsigned short* Kth = Khp + (size_t)kb * HD;
        const unsigned short* Ktl = Klp + (size_t)kb * HD;
#pragma unroll
        for (int l = 0; l < 5; ++l) {
            int idx = tid + l * 256;     // 64 keys x 20 chunks of 4 shorts
            int ky = idx / 20, fc = idx % 20;
            *reinterpret_cast<short4v*>(&kv_hi[ky * KSTR + fc * 4]) =
                *reinterpret_cast<const short4v*>(&Kth[ky * HD + fc * 4]);
            *reinterpret_cast<short4v*>(&kv_lo[ky * KSTR + fc * 4]) =
                *reinterpret_cast<const short4v*>(&Ktl[ky * HD + fc * 4]);
        }
        {   // zero-fill dims 80..95 (both planes)
            int ky = tid >> 2, off = (tid & 3) << 2;
            uint2 z; z.x = 0u; z.y = 0u;
            *reinterpret_cast<uint2*>(&kv_hi[ky * KSTR + 80 + off]) = z;
            *reinterpret_cast<uint2*>(&kv_lo[ky * KSTR + 80 + off]) = z;
        }
        __syncthreads();

        // ---- QK^T: S fragments (col=key, row=lg*4+q)
        f32x4 sfr[4];
#pragma unroll
        for (int kt = 0; kt < 4; ++kt) {
            f32x4 s = (f32x4){0.f, 0.f, 0.f, 0.f};
#pragma unroll
            for (int kc = 0; kc < 3; ++kc) {
                int bidx = (kt * 16 + col) * KSTR + kc * 32 + lg * 8;
                short8v khf = *reinterpret_cast<const short8v*>(&kv_hi[bidx]);
                short8v klf = *reinterpret_cast<const short8v*>(&kv_lo[bidx]);
                s = __builtin_amdgcn_mfma_f32_16x16x32_bf16(qfh[kc], khf, s, 0, 0, 0);
                s = __builtin_amdgcn_mfma_f32_16x16x32_bf16(qfl[kc], khf, s, 0, 0, 0);
                s = __builtin_amdgcn_mfma_f32_16x16x32_bf16(qfh[kc], klf, s, 0, 0, 0);
            }
            sfr[kt] = s;
        }
        __syncthreads();                 // all K reads done -> kv free for V

        // ---- issue V loads early (8B each, latency hides under softmax)
        short4v vrh[5], vrl[5];
#pragma unroll
        for (int l = 0; l < 5; ++l) {
            int idx = tid + l * 256;     // d = idx/16, kg = idx%16
            int d = idx >> 4, kg = idx & 15;
            vrh[l] = *reinterpret_cast<const short4v*>(&Vhp[(size_t)d * SEQL + kb + kg * 4]);
            vrl[l] = *reinterpret_cast<const short4v*>(&Vlp[(size_t)d * SEQL + kb + kg * 4]);
        }

        // ---- online softmax (identical to validated kernel)
#pragma unroll
        for (int q = 0; q < 4; ++q) {
            float sv[4];
            float mx = -1e30f;
#pragma unroll
            for (int kt = 0; kt < 4; ++kt) {
                int key = kb + kt * 16 + col;
                bool ok = (key >= qstart[q]) && (key < qend[q]);
                sv[kt] = ok ? sfr[kt][q] : -1e30f;
                mx = fmaxf(mx, sv[kt]);
            }
            mx = fmaxf(mx, __shfl_xor(mx, 1));
            mx = fmaxf(mx, __shfl_xor(mx, 2));
            mx = fmaxf(mx, __shfl_xor(mx, 4));
            mx = fmaxf(mx, __shfl_xor(mx, 8));
            float mnew  = fmaxf(mrun[q], mx);
            float alpha = __expf(mrun[q] - mnew);
            float ps = 0.f;
            int prow = (wrow + lg * 4 + q) * PSTR;
#pragma unroll
            for (int kt = 0; kt < 4; ++kt) {
                float p = (sv[kt] > -1e29f) ? __expf(sv[kt] - mnew) : 0.f;
                ps += p;
                unsigned short ph = f2bf(p);
                p_hi[prow + kt * 16 + col] = ph;
                p_lo[prow + kt * 16 + col] = f2bf(p - bf2f(ph));
            }
            ps += __shfl_xor(ps, 1);
            ps += __shfl_xor(ps, 2);
            ps += __shfl_xor(ps, 4);
            ps += __shfl_xor(ps, 8);
            lrun[q] = lrun[q] * alpha + ps;
            mrun[q] = mnew;
#pragma unroll
            for (int fn = 0; fn < 5; ++fn) oacc[fn][q] *= alpha;
        }

        // ---- write V tile to LDS [d][72]: pure 8B copies
#pragma unroll
        for (int l = 0; l < 5; ++l) {
            int idx = tid + l * 256;
            int d = idx >> 4, kg = idx & 15;
            *reinterpret_cast<short4v*>(&kv_hi[d * VSTR + kg * 4]) = vrh[l];
            *reinterpret_cast<short4v*>(&kv_lo[d * VSTR + kg * 4]) = vrl[l];
        }
        __syncthreads();                 // V + P ready

        // ---- PV: O += P * V (identical)
#pragma unroll
        for (int kc2 = 0; kc2 < 2; ++kc2) {
            int aidx = (wrow + col) * PSTR + kc2 * 32 + lg * 8;
            short8v pah = *reinterpret_cast<const short8v*>(&p_hi[aidx]);
            short8v pal = *reinterpret_cast<const short8v*>(&p_lo[aidx]);
#pragma unroll
            for (int fn = 0; fn < 5; ++fn) {
                int bidx = (fn * 16 + col) * VSTR + kc2 * 32 + lg * 8;
                short8v vh = *reinterpret_cast<const short8v*>(&kv_hi[bidx]);
                short8v vl = *reinterpret_cast<const short8v*>(&kv_lo[bidx]);
                oacc[fn] = __builtin_amdgcn_mfma_f32_16x16x32_bf16(pah, vh, oacc[fn], 0, 0, 0);
                oacc[fn] = __builtin_amdgcn_mfma_f32_16x16x32_bf16(pal, vh, oacc[fn], 0, 0, 0);
                oacc[fn] = __builtin_amdgcn_mfma_f32_16x16x32_bf16(pah, vl, oacc[fn], 0, 0, 0);
            }
        }
    }

    // ---- epilogue: ctx planes
#pragma unroll
    for (int q = 0; q < 4; ++q) {
        float inv = 1.f / lrun[q];
        size_t rowoff = (size_t)(r0 + wrow + lg * 4 + q) * EMBED + h * HD;
#pragma unroll
        for (int fn = 0; fn < 5; ++fn) {
            float val = oacc[fn][q] * inv;
            unsigned short hb = f2bf(val);
            ctxh[rowoff + fn * 16 + col] = hb;
            ctxl[rowoff + fn * 16 + col] = f2bf(val - bf2f(hb));
        }
    }
}

// ---------------------------------------------------------------------------
extern "C" void kernel_launch(void* const* d_in, const int* in_sizes, int n_in,
                              void* d_out, int out_size, void* d_ws, size_t ws_size,
                              hipStream_t stream)
{
    const float* x      = (const float*)d_in[0];
    const float* rpe    = (const float*)d_in[1];
    const int*   cu     = (const int*)d_in[2];
    // d_in[3] = max_seqlen (unused)
    const float* qkv_w  = (const float*)d_in[4];
    const float* qkv_b  = (const float*)d_in[5];
    const float* proj_w = (const float*)d_in[6];
    const float* proj_b = (const float*)d_in[7];

    const int nseg = in_sizes[2] - 1;
    char* wsb = (char*)d_ws;

    const bool HOIST = ws_size >= 68157440ULL;

    if (HOIST) {
        // G0 [0 .. 20.97M): Q fp32 | K fp32; after rotary -> ctx planes
        float* Qf = (float*)wsb;
        float* Kf = (float*)(wsb + 10485760);
        unsigned short* ctxh = (unsigned short*)wsb;              // overlays Qf
        unsigned short* ctxl = (unsigned short*)(wsb + 5242880);
        // G1 [20.97M .. 31.46M): V^T planes
        unsigned short* vth = (unsigned short*)(wsb + 20971520);
        unsigned short* vtl = (unsigned short*)(wsb + 26214400);
        // G2 [31.46M .. 61.60M): x planes + qkv_w planes; after QKV GEMM ->
        //                        q/k planes (rotary output)
        unsigned short* xh = (unsigned short*)(wsb + 31457280);
        unsigned short* xl = (unsigned short*)(wsb + 36700160);
        unsigned short* wh = (unsigned short*)(wsb + 41943040);
        unsigned short* wl = (unsigned short*)(wsb + 51773440);
        unsigned short* qph = (unsigned short*)(wsb + 31457280);  // overlays xh
        unsigned short* qpl = (unsigned short*)(wsb + 36700160);
        unsigned short* kph = (unsigned short*)(wsb + 41943040);  // overlays wh
        unsigned short* kpl = (unsigned short*)(wsb + 47185920);
        // G3 [61.60M .. 68.16M): proj_w planes
        unsigned short* ph = (unsigned short*)(wsb + 61603840);
        unsigned short* pl = (unsigned short*)(wsb + 64880640);

        const int c0 = SEQL * EMBED / 4, c1 = QKV_N * EMBED / 4, c2 = EMBED * EMBED / 4;

        // 0) pre-split x / qkv_w / proj_w
        split3_kernel<<<(c0 + c1 + c2 + 255) / 256, 256, 0, stream>>>(
            x, xh, xl, c0, qkv_w, wh, wl, c1, proj_w, ph, pl, c2);

        // 1) QKV projection: Q,K -> fp32; V -> V^T bf16 planes
        gemm_mfma_pre_kernel<1><<<dim3(QKV_N / 128, SEQL / 128), 256, 0, stream>>>(
            xh, xl, wh, wl, qkv_b, Qf, vth, vtl, SEQL, QKV_N, EMBED);

        // 2) rotary + scale-fold + bf16 split -> q/k planes (x/w dead)
        rotary_split_kernel<<<(2 * NHEAD * SEQL * ROT) / 256, 256, 0, stream>>>(
            Qf, Kf, rpe, qph, qpl, kph, kpl);

        // 3) attention from planes -> ctx planes (Q/K fp32 dead)
        attn_mfma2_kernel<<<dim3(SEQL / 64, NHEAD), 256, 0, stream>>>(
            qph, qpl, kph, kpl, vth, vtl, cu, nseg, ctxh, ctxl);

        // 4) output projection
        gemm_mfma_pre_kernel<0><<<dim3(EMBED / 128, SEQL / 128), 256, 0, stream>>>(
            ctxh, ctxl, ph, pl, proj_b, (float*)d_out, nullptr, nullptr,
            SEQL, EMBED, EMBED);
    } else {
        // fallback: fully-validated round-3 pipeline with round-4 attention
        float* ws  = (float*)d_ws;
        float* Q   = ws;
        float* K   = ws + (size_t)QKV_STRIDE;
        float* V   = ws + (size_t)2 * QKV_STRIDE;
        float* ctx = ws + (size_t)3 * QKV_STRIDE;
        gemm_mfma_kernel<1><<<dim3(QKV_N / 128, SEQL / 128), 256, 0, stream>>>(
            x, qkv_w, qkv_b, Q, SEQL, QKV_N, EMBED);
        rotary_kernel<<<(2 * NHEAD * SEQL * ROT) / 256, 256, 0, stream>>>(Q, K, rpe);
        attn_mfma_kernel<0><<<dim3(SEQL / 64, NHEAD), 256, 0, stream>>>(
            Q, K, V, cu, nseg, ctx, nullptr, nullptr);
        gemm_mfma_kernel<0><<<dim3(EMBED / 128, SEQL / 128), 256, 0, stream>>>(
            ctx, proj_w, proj_b, (float*)d_out, SEQL, EMBED, EMBED);
    }
}